// Round 11
// baseline (180.531 us; speedup 1.0000x reference)
//
#include <hip/hip_runtime.h>

#define N_NODES 100000
#define F 128
#define NE 1600000
#define NBUCK 256
#define BSZ 391                    // nodes per bucket; 391*256 = 100096 >= N
#define CHUNK2 (NE / NBUCK)        // 6250 edges per partition chunk
#define SEGCAP 16384               // LDS col-segment capacity (worst ~12.5K)
#define SCAN_CHUNK 512
#define SCAN_BLOCKS ((N_NODES + SCAN_CHUNK - 1) / SCAN_CHUNK)  // 196
#define PAD16(v) (((v) + 15) & ~15)

typedef __attribute__((ext_vector_type(8))) short bf16x8;
typedef __attribute__((ext_vector_type(4))) float f32x4;

// fp32 -> bf16 round-to-nearest-even
__device__ __forceinline__ unsigned short f2bf(float f) {
    unsigned int u = __float_as_uint(f);
    return (unsigned short)((u + 0x7FFFu + ((u >> 16) & 1u)) >> 16);
}
__device__ __forceinline__ float blo(unsigned int v) { return __uint_as_float(v << 16); }
__device__ __forceinline__ float bhi(unsigned int v) { return __uint_as_float(v & 0xFFFF0000u); }

// ---------- Kernel 1: support(bf16) = x @ W via MFMA. 128x128 tile, 4 waves ----------
__global__ __launch_bounds__(256) void gemm_mfma(const float* __restrict__ x,
                                                 const float* __restrict__ w,
                                                 ushort* __restrict__ sup) {
    __shared__ ushort xs[128 * 128];   // 32 KB  [m][k]
    __shared__ ushort wt[128 * 128];   // 32 KB  [n][k]  (W transposed)
    const int t = threadIdx.x;
    const int rbase = blockIdx.x * 128;

#pragma unroll
    for (int it = 0; it < 16; ++it) {
        const int f = it * 256 + t;
        const int c = f & 127;
        const int kq = f >> 7;
        ushort4 o;
        o.x = f2bf(w[(4 * kq + 0) * F + c]);
        o.y = f2bf(w[(4 * kq + 1) * F + c]);
        o.z = f2bf(w[(4 * kq + 2) * F + c]);
        o.w = f2bf(w[(4 * kq + 3) * F + c]);
        ((ushort4*)wt)[c * 32 + (kq ^ ((c & 15) << 1))] = o;
    }
#pragma unroll
    for (int it = 0; it < 16; ++it) {
        const int f = it * 256 + t;
        const int r = f >> 5;
        const int cg = f & 31;
        const int gr = rbase + r;
        float4 v = make_float4(0.f, 0.f, 0.f, 0.f);
        if (gr < N_NODES) v = ((const float4*)x)[(long long)gr * 32 + cg];
        ushort4 o;
        o.x = f2bf(v.x); o.y = f2bf(v.y); o.z = f2bf(v.z); o.w = f2bf(v.w);
        ((ushort4*)xs)[r * 32 + (cg ^ ((r & 15) << 1))] = o;
    }
    __syncthreads();

    const int wid = t >> 6;
    const int lane = t & 63;
    const int wr = wid >> 1;
    const int wc = wid & 1;
    const int l16 = lane & 15;
    const int kg = lane >> 4;

    f32x4 acc[4][4] = {};
    const bf16x8* xs8 = (const bf16x8*)xs;
    const bf16x8* wt8 = (const bf16x8*)wt;

#pragma unroll
    for (int ks = 0; ks < 4; ++ks) {
        const int k8 = ks * 4 + kg;
        bf16x8 a[4], bb[4];
#pragma unroll
        for (int mi = 0; mi < 4; ++mi) {
            const int r = wr * 64 + mi * 16 + l16;
            a[mi] = xs8[r * 16 + (k8 ^ (r & 15))];
        }
#pragma unroll
        for (int ni = 0; ni < 4; ++ni) {
            const int c = wc * 64 + ni * 16 + l16;
            bb[ni] = wt8[c * 16 + (k8 ^ (c & 15))];
        }
#pragma unroll
        for (int mi = 0; mi < 4; ++mi)
#pragma unroll
            for (int ni = 0; ni < 4; ++ni)
                acc[mi][ni] = __builtin_amdgcn_mfma_f32_16x16x32_bf16(
                    a[mi], bb[ni], acc[mi][ni], 0, 0, 0);
    }

#pragma unroll
    for (int mi = 0; mi < 4; ++mi) {
#pragma unroll
        for (int reg = 0; reg < 4; ++reg) {
            const int r = rbase + wr * 64 + mi * 16 + kg * 4 + reg;
            if (r < N_NODES) {
#pragma unroll
                for (int ni = 0; ni < 4; ++ni) {
                    const int c = wc * 64 + ni * 16 + l16;
                    sup[(long long)r * F + c] = f2bf(acc[mi][ni][reg]);
                }
            }
        }
    }
}

// ---------- A1: per-chunk bucket histogram (256 bins, 1 KB LDS) ----------
__global__ __launch_bounds__(1024) void bucket_hist(const int* __restrict__ dst,
                                                    int* __restrict__ C) {
    __shared__ int cnt[NBUCK];
    if (threadIdx.x < NBUCK) cnt[threadIdx.x] = 0;
    __syncthreads();
    const int e0 = blockIdx.x * CHUNK2;
    for (int i = threadIdx.x; i < CHUNK2; i += 1024)
        atomicAdd(&cnt[dst[e0 + i] / BSZ], 1);
    __syncthreads();
    if (threadIdx.x < NBUCK) C[blockIdx.x * NBUCK + threadIdx.x] = cnt[threadIdx.x];
}

// ---------- A2: offsets O[b][k] = bstart[k] + prefix_b C[b][k]; bucket starts ----------
__global__ void bucket_scan(const int* __restrict__ C, int* __restrict__ O,
                            int* __restrict__ bstart) {
    __shared__ int sh[NBUCK];
    const int k = threadIdx.x;   // one thread per bucket
    int run = 0;
    for (int b = 0; b < NBUCK; ++b) {
        O[b * NBUCK + k] = run;
        run += C[b * NBUCK + k];
    }
    const int tot = run;
    sh[k] = tot;
    __syncthreads();
    for (int off = 1; off < NBUCK; off <<= 1) {
        const int u = (k >= off) ? sh[k - off] : 0;
        __syncthreads();
        sh[k] += u;
        __syncthreads();
    }
    const int base = sh[k] - tot;  // exclusive
    bstart[k] = base;
    if (k == NBUCK - 1) bstart[NBUCK] = sh[k];
    for (int b = 0; b < NBUCK; ++b) O[b * NBUCK + k] += base;
}

// ---------- A3: partition edges into buckets (contiguous runs per (block,bucket)) ----------
__global__ __launch_bounds__(1024) void bucket_scatter(const int* __restrict__ src,
                                                       const int* __restrict__ dst,
                                                       const int* __restrict__ O,
                                                       int* __restrict__ Psrc,
                                                       unsigned short* __restrict__ Pdl) {
    __shared__ int off[NBUCK];
    __shared__ int cnt[NBUCK];
    if (threadIdx.x < NBUCK) {
        off[threadIdx.x] = O[blockIdx.x * NBUCK + threadIdx.x];
        cnt[threadIdx.x] = 0;
    }
    __syncthreads();
    const int e0 = blockIdx.x * CHUNK2;
    for (int i = threadIdx.x; i < CHUNK2; i += 1024) {
        const int d = dst[e0 + i];
        const int k = d / BSZ;
        const int r = atomicAdd(&cnt[k], 1);
        const int pos = off[k] + r;
        Psrc[pos] = src[e0 + i];
        Pdl[pos] = (unsigned short)(d - k * BSZ);
    }
}

// ---------- B1: per-bucket degree histogram -> deg (coalesced) ----------
__global__ void deg_hist(const unsigned short* __restrict__ Pdl,
                         const int* __restrict__ bstart,
                         int* __restrict__ deg) {
    __shared__ int c[BSZ];
    const int k = blockIdx.x;
    for (int i = threadIdx.x; i < BSZ; i += blockDim.x) c[i] = 0;
    __syncthreads();
    const int s = bstart[k], e = bstart[k + 1];
    for (int i = s + threadIdx.x; i < e; i += blockDim.x)
        atomicAdd(&c[Pdl[i]], 1);
    __syncthreads();
    const int n0 = k * BSZ;
    for (int i = threadIdx.x; i < BSZ; i += blockDim.x)
        if (n0 + i < N_NODES) deg[n0 + i] = c[i];
}

// ---------- Scan kernels: two-level exclusive scan over PADDED deg -> row_ptr ----------
__global__ void scan_partial(const int* __restrict__ deg, int* __restrict__ bsum) {
    __shared__ int red[256];
    const int t = threadIdx.x;
    const int base = blockIdx.x * SCAN_CHUNK;
    int s = 0;
    for (int i = t; i < SCAN_CHUNK; i += 256) {
        const int idx = base + i;
        if (idx < N_NODES) s += PAD16(deg[idx]);
    }
    red[t] = s;
    __syncthreads();
    for (int off = 128; off > 0; off >>= 1) {
        if (t < off) red[t] += red[t + off];
        __syncthreads();
    }
    if (t == 0) bsum[blockIdx.x] = red[0];
}

__global__ void scan_bsum(const int* __restrict__ bsum, int* __restrict__ boff,
                          int* __restrict__ row_ptr) {
    __shared__ int sh[256];
    const int t = threadIdx.x;
    const int v = (t < SCAN_BLOCKS) ? bsum[t] : 0;
    sh[t] = v;
    __syncthreads();
    for (int off = 1; off < 256; off <<= 1) {
        const int u = (t >= off) ? sh[t - off] : 0;
        __syncthreads();
        sh[t] += u;
        __syncthreads();
    }
    if (t < SCAN_BLOCKS) boff[t] = sh[t] - v;
    if (t == SCAN_BLOCKS - 1) row_ptr[N_NODES] = sh[t];  // padded total
}

__global__ void scan_apply(const int* __restrict__ deg, const int* __restrict__ boff,
                           int* __restrict__ row_ptr) {
    __shared__ int sh[256];
    const int t = threadIdx.x;
    const int base = blockIdx.x * SCAN_CHUNK;
    const int i0 = base + t * 2;
    const int d0p = (i0 < N_NODES) ? PAD16(deg[i0]) : 0;
    const int d1p = (i0 + 1 < N_NODES) ? PAD16(deg[i0 + 1]) : 0;
    const int tsum = d0p + d1p;
    sh[t] = tsum;
    __syncthreads();
    for (int off = 1; off < 256; off <<= 1) {
        const int u = (t >= off) ? sh[t - off] : 0;
        __syncthreads();
        sh[t] += u;
        __syncthreads();
    }
    const int texcl = sh[t] - tsum + boff[blockIdx.x];
    if (i0 < N_NODES) row_ptr[i0] = texcl;
    if (i0 + 1 < N_NODES) row_ptr[i0 + 1] = texcl + d0p;
}

// ---------- B2: per-bucket CSR fill in LDS, coalesced dump ----------
__global__ __launch_bounds__(1024) void col_fill(const int* __restrict__ Psrc,
                                                 const unsigned short* __restrict__ Pdl,
                                                 const int* __restrict__ bstart,
                                                 const int* __restrict__ row_ptr,
                                                 int* __restrict__ col) {
    __shared__ int buf[SEGCAP];    // 64 KB
    __shared__ int rp[BSZ + 1];
    __shared__ int cnt[BSZ];
    const int k = blockIdx.x;
    const int n0 = k * BSZ;
    const int nEnd = min(N_NODES, n0 + BSZ);
    const int nn = nEnd - n0;
    for (int i = threadIdx.x; i <= nn; i += 1024) rp[i] = row_ptr[n0 + i];
    for (int i = threadIdx.x; i < nn; i += 1024) cnt[i] = 0;
    __syncthreads();
    const int segbase = rp[0];
    const int seglen = rp[nn] - segbase;           // multiple of 16
    for (int i = threadIdx.x; i < seglen; i += 1024) buf[i] = N_NODES;  // pad = zero row
    __syncthreads();
    const int s = bstart[k], e = bstart[k + 1];
    for (int i = s + threadIdx.x; i < e; i += 1024) {
        const int dl = Pdl[i];
        const int r = atomicAdd(&cnt[dl], 1);
        buf[rp[dl] - segbase + r] = Psrc[i];
    }
    __syncthreads();
    for (int i = threadIdx.x; i < (seglen >> 2); i += 1024)
        ((int4*)(col + segbase))[i] = ((const int4*)buf)[i];
}

// ---------- Kernel 5: gather-aggregate, branchless 16-edge groups (R10, verified) ----------
__global__ __launch_bounds__(256) void aggregate_kernel(
    const ushort* __restrict__ sup,
    const int* __restrict__ row_ptr,
    const int* __restrict__ degv,
    const int* __restrict__ col,
    const float* __restrict__ b,
    float* __restrict__ out) {
    const int wid = threadIdx.x >> 6;
    const int lane = threadIdx.x & 63;
    const int node = blockIdx.x * 4 + wid;
    if (node >= N_NODES) return;

    const int rs = lane >> 4;   // row slot 0..3
    const int fq = lane & 15;   // feature quad

    const int beg = row_ptr[node];
    const int end = row_ptr[node + 1];   // padded: (end-beg) % 16 == 0

    const uint4* sp = (const uint4*)sup;

    float acc[8] = {};
    for (int base = beg; base < end; base += 64) {
        const int rem = end - base;
        const int m = rem < 64 ? rem : 64;                 // in {16,32,48,64}
        const int mycol = (lane < m) ? col[base + lane] : 0;
        const int ng = m >> 4;
        for (int g = 0; g < ng; ++g) {
            uint4 v[4];
#pragma unroll
            for (int q = 0; q < 4; ++q) {
                const int s = __shfl(mycol, g * 16 + q * 4 + rs);
                v[q] = sp[(long long)s * 16 + fq];         // pads read zero row
            }
#pragma unroll
            for (int q = 0; q < 4; ++q) {
                acc[0] += blo(v[q].x); acc[1] += bhi(v[q].x);
                acc[2] += blo(v[q].y); acc[3] += bhi(v[q].y);
                acc[4] += blo(v[q].z); acc[5] += bhi(v[q].z);
                acc[6] += blo(v[q].w); acc[7] += bhi(v[q].w);
            }
        }
    }
    // reduce across the 4 row slots FIRST...
#pragma unroll
    for (int i = 0; i < 8; ++i) {
        acc[i] += __shfl_xor(acc[i], 16);
        acc[i] += __shfl_xor(acc[i], 32);
    }
    // ...THEN add self-loop exactly once
    {
        const uint4 v = sp[(long long)node * 16 + fq];
        acc[0] += blo(v.x); acc[1] += bhi(v.x);
        acc[2] += blo(v.y); acc[3] += bhi(v.y);
        acc[4] += blo(v.z); acc[5] += bhi(v.z);
        acc[6] += blo(v.w); acc[7] += bhi(v.w);
    }
    const float inv = 1.0f / (float)(degv[node] + 1);      // REAL degree for the mean
    const float4 b0 = ((const float4*)b)[fq * 2];
    const float4 b1 = ((const float4*)b)[fq * 2 + 1];
    if (rs == 0) {
        float4 r0, r1;
        r0.x = acc[0] * inv + b0.x; r0.y = acc[1] * inv + b0.y;
        r0.z = acc[2] * inv + b0.z; r0.w = acc[3] * inv + b0.w;
        r1.x = acc[4] * inv + b1.x; r1.y = acc[5] * inv + b1.y;
        r1.z = acc[6] * inv + b1.z; r1.w = acc[7] * inv + b1.w;
        float4* o4 = (float4*)out;
        o4[(long long)node * 32 + fq * 2] = r0;
        o4[(long long)node * 32 + fq * 2 + 1] = r1;
    }
}

extern "C" void kernel_launch(void* const* d_in, const int* in_sizes, int n_in,
                              void* d_out, int out_size, void* d_ws, size_t ws_size,
                              hipStream_t stream) {
    const float* x = (const float*)d_in[0];
    const int* src = (const int*)d_in[1];
    const int* dst = (const int*)d_in[2];
    const float* w = (const float*)d_in[3];
    const float* b = (const float*)d_in[4];
    float* out = (float*)d_out;

    // Workspace (~49 MB): sup 25.6 | deg .4 | row_ptr .4 | col 12.4 | Psrc 6.4 | Pdl 3.2 | C/O .5
    char* p = (char*)d_ws;
    ushort* sup = (ushort*)p;    p += (((size_t)(N_NODES + 1)) * F * sizeof(ushort) + 15) & ~15ULL;
    int* deg = (int*)p;          p += ((size_t)N_NODES * sizeof(int) + 15) & ~15ULL;
    int* row_ptr = (int*)p;      p += (((size_t)N_NODES + 1) * sizeof(int) + 15) & ~15ULL;
    int* col = (int*)p;          p += ((size_t)(NE + 15 * N_NODES) * sizeof(int) + 15) & ~15ULL;
    int* Psrc = (int*)p;         p += ((size_t)NE * sizeof(int) + 15) & ~15ULL;
    unsigned short* Pdl = (unsigned short*)p;  p += ((size_t)NE * sizeof(unsigned short) + 15) & ~15ULL;
    int* C = (int*)p;            p += ((size_t)NBUCK * NBUCK * sizeof(int) + 15) & ~15ULL;
    int* O = (int*)p;            p += ((size_t)NBUCK * NBUCK * sizeof(int) + 15) & ~15ULL;
    int* bstart = (int*)p;       p += (((size_t)NBUCK + 1) * sizeof(int) + 15) & ~15ULL;
    int* bsum = (int*)p;         p += ((size_t)SCAN_BLOCKS * sizeof(int) + 15) & ~15ULL;
    int* boff = (int*)p;

    // zero row at index N_NODES (pad gathers read it)
    hipMemsetAsync(sup + (size_t)N_NODES * F, 0, F * sizeof(ushort), stream);

    gemm_mfma<<<(N_NODES + 127) / 128, 256, 0, stream>>>(x, w, sup);
    bucket_hist<<<NBUCK, 1024, 0, stream>>>(dst, C);
    bucket_scan<<<1, NBUCK, 0, stream>>>(C, O, bstart);
    bucket_scatter<<<NBUCK, 1024, 0, stream>>>(src, dst, O, Psrc, Pdl);
    deg_hist<<<NBUCK, 256, 0, stream>>>(Pdl, bstart, deg);
    scan_partial<<<SCAN_BLOCKS, 256, 0, stream>>>(deg, bsum);
    scan_bsum<<<1, 256, 0, stream>>>(bsum, boff, row_ptr);
    scan_apply<<<SCAN_BLOCKS, 256, 0, stream>>>(deg, boff, row_ptr);
    col_fill<<<NBUCK, 1024, 0, stream>>>(Psrc, Pdl, bstart, row_ptr, col);
    aggregate_kernel<<<(N_NODES + 3) / 4, 256, 0, stream>>>(sup, row_ptr, deg, col, b, out);
}

// Round 12
// 142.815 us; speedup vs baseline: 1.2641x; 1.2641x over previous
//
#include <hip/hip_runtime.h>

#define N_NODES 100000
#define F 128
#define NE 1600000
#define NBUCK 256
#define BSZ 391                    // nodes per bucket; 391*256 = 100096 >= N
#define CHUNK2 (NE / NBUCK)        // 6250 edges per partition chunk
#define SEGCAP 16384               // LDS col-segment capacity (worst ~12.5K)
#define SCAN_CHUNK 512
#define SCAN_BLOCKS ((N_NODES + SCAN_CHUNK - 1) / SCAN_CHUNK)  // 196
#define PAD16(v) (((v) + 15) & ~15)

typedef __attribute__((ext_vector_type(8))) short bf16x8;
typedef __attribute__((ext_vector_type(4))) float f32x4;

// fp32 -> bf16 round-to-nearest-even
__device__ __forceinline__ unsigned short f2bf(float f) {
    unsigned int u = __float_as_uint(f);
    return (unsigned short)((u + 0x7FFFu + ((u >> 16) & 1u)) >> 16);
}
__device__ __forceinline__ float blo(unsigned int v) { return __uint_as_float(v << 16); }
__device__ __forceinline__ float bhi(unsigned int v) { return __uint_as_float(v & 0xFFFF0000u); }

// ---------- Kernel 1: support(bf16) = x @ W via MFMA. 128x128 tile, 4 waves ----------
__global__ __launch_bounds__(256) void gemm_mfma(const float* __restrict__ x,
                                                 const float* __restrict__ w,
                                                 ushort* __restrict__ sup) {
    __shared__ ushort xs[128 * 128];   // 32 KB  [m][k]
    __shared__ ushort wt[128 * 128];   // 32 KB  [n][k]  (W transposed)
    const int t = threadIdx.x;
    const int rbase = blockIdx.x * 128;

#pragma unroll
    for (int it = 0; it < 16; ++it) {
        const int f = it * 256 + t;
        const int c = f & 127;
        const int kq = f >> 7;
        ushort4 o;
        o.x = f2bf(w[(4 * kq + 0) * F + c]);
        o.y = f2bf(w[(4 * kq + 1) * F + c]);
        o.z = f2bf(w[(4 * kq + 2) * F + c]);
        o.w = f2bf(w[(4 * kq + 3) * F + c]);
        ((ushort4*)wt)[c * 32 + (kq ^ ((c & 15) << 1))] = o;
    }
#pragma unroll
    for (int it = 0; it < 16; ++it) {
        const int f = it * 256 + t;
        const int r = f >> 5;
        const int cg = f & 31;
        const int gr = rbase + r;
        float4 v = make_float4(0.f, 0.f, 0.f, 0.f);
        if (gr < N_NODES) v = ((const float4*)x)[(long long)gr * 32 + cg];
        ushort4 o;
        o.x = f2bf(v.x); o.y = f2bf(v.y); o.z = f2bf(v.z); o.w = f2bf(v.w);
        ((ushort4*)xs)[r * 32 + (cg ^ ((r & 15) << 1))] = o;
    }
    __syncthreads();

    const int wid = t >> 6;
    const int lane = t & 63;
    const int wr = wid >> 1;
    const int wc = wid & 1;
    const int l16 = lane & 15;
    const int kg = lane >> 4;

    f32x4 acc[4][4] = {};
    const bf16x8* xs8 = (const bf16x8*)xs;
    const bf16x8* wt8 = (const bf16x8*)wt;

#pragma unroll
    for (int ks = 0; ks < 4; ++ks) {
        const int k8 = ks * 4 + kg;
        bf16x8 a[4], bb[4];
#pragma unroll
        for (int mi = 0; mi < 4; ++mi) {
            const int r = wr * 64 + mi * 16 + l16;
            a[mi] = xs8[r * 16 + (k8 ^ (r & 15))];
        }
#pragma unroll
        for (int ni = 0; ni < 4; ++ni) {
            const int c = wc * 64 + ni * 16 + l16;
            bb[ni] = wt8[c * 16 + (k8 ^ (c & 15))];
        }
#pragma unroll
        for (int mi = 0; mi < 4; ++mi)
#pragma unroll
            for (int ni = 0; ni < 4; ++ni)
                acc[mi][ni] = __builtin_amdgcn_mfma_f32_16x16x32_bf16(
                    a[mi], bb[ni], acc[mi][ni], 0, 0, 0);
    }

#pragma unroll
    for (int mi = 0; mi < 4; ++mi) {
#pragma unroll
        for (int reg = 0; reg < 4; ++reg) {
            const int r = rbase + wr * 64 + mi * 16 + kg * 4 + reg;
            if (r < N_NODES) {
#pragma unroll
                for (int ni = 0; ni < 4; ++ni) {
                    const int c = wc * 64 + ni * 16 + l16;
                    sup[(long long)r * F + c] = f2bf(acc[mi][ni][reg]);
                }
            }
        }
    }
}

// ---------- A1: per-chunk bucket histogram (256 bins, 1 KB LDS) ----------
__global__ __launch_bounds__(1024) void bucket_hist(const int* __restrict__ dst,
                                                    int* __restrict__ C) {
    __shared__ int cnt[NBUCK];
    if (threadIdx.x < NBUCK) cnt[threadIdx.x] = 0;
    __syncthreads();
    const int e0 = blockIdx.x * CHUNK2;
    for (int i = threadIdx.x; i < CHUNK2; i += 1024)
        atomicAdd(&cnt[dst[e0 + i] / BSZ], 1);
    __syncthreads();
    if (threadIdx.x < NBUCK) C[blockIdx.x * NBUCK + threadIdx.x] = cnt[threadIdx.x];
}

// ---------- A2a: per-bucket column scan over chunks (256 blocks, parallel) ----------
__global__ __launch_bounds__(NBUCK) void bucket_scan_cols(const int* __restrict__ C,
                                                          int* __restrict__ O,
                                                          int* __restrict__ colsum) {
    __shared__ int sh[NBUCK];
    const int k = blockIdx.x;    // bucket
    const int b = threadIdx.x;   // chunk
    const int v = C[b * NBUCK + k];
    sh[b] = v;
    __syncthreads();
    for (int off = 1; off < NBUCK; off <<= 1) {
        const int u = (b >= off) ? sh[b - off] : 0;
        __syncthreads();
        sh[b] += u;
        __syncthreads();
    }
    O[b * NBUCK + k] = sh[b] - v;            // exclusive prefix within bucket
    if (b == NBUCK - 1) colsum[k] = sh[b];   // bucket total
}

// ---------- A2b: scan bucket totals -> bstart (tiny single block) ----------
__global__ __launch_bounds__(NBUCK) void bucket_scan_tot(const int* __restrict__ colsum,
                                                         int* __restrict__ bstart) {
    __shared__ int sh[NBUCK];
    const int t = threadIdx.x;
    const int v = colsum[t];
    sh[t] = v;
    __syncthreads();
    for (int off = 1; off < NBUCK; off <<= 1) {
        const int u = (t >= off) ? sh[t - off] : 0;
        __syncthreads();
        sh[t] += u;
        __syncthreads();
    }
    bstart[t] = sh[t] - v;
    if (t == NBUCK - 1) bstart[NBUCK] = sh[t];
}

// ---------- A3: partition edges into buckets (contiguous runs per (block,bucket)) ----------
__global__ __launch_bounds__(1024) void bucket_scatter(const int* __restrict__ src,
                                                       const int* __restrict__ dst,
                                                       const int* __restrict__ O,
                                                       const int* __restrict__ bstart,
                                                       int* __restrict__ Psrc,
                                                       unsigned short* __restrict__ Pdl) {
    __shared__ int off[NBUCK];
    __shared__ int cnt[NBUCK];
    if (threadIdx.x < NBUCK) {
        off[threadIdx.x] = O[blockIdx.x * NBUCK + threadIdx.x] + bstart[threadIdx.x];
        cnt[threadIdx.x] = 0;
    }
    __syncthreads();
    const int e0 = blockIdx.x * CHUNK2;
    for (int i = threadIdx.x; i < CHUNK2; i += 1024) {
        const int d = dst[e0 + i];
        const int k = d / BSZ;
        const int r = atomicAdd(&cnt[k], 1);
        const int pos = off[k] + r;
        Psrc[pos] = src[e0 + i];
        Pdl[pos] = (unsigned short)(d - k * BSZ);
    }
}

// ---------- B1: per-bucket degree histogram -> deg (coalesced) ----------
__global__ void deg_hist(const unsigned short* __restrict__ Pdl,
                         const int* __restrict__ bstart,
                         int* __restrict__ deg) {
    __shared__ int c[BSZ];
    const int k = blockIdx.x;
    for (int i = threadIdx.x; i < BSZ; i += blockDim.x) c[i] = 0;
    __syncthreads();
    const int s = bstart[k], e = bstart[k + 1];
    for (int i = s + threadIdx.x; i < e; i += blockDim.x)
        atomicAdd(&c[Pdl[i]], 1);
    __syncthreads();
    const int n0 = k * BSZ;
    for (int i = threadIdx.x; i < BSZ; i += blockDim.x)
        if (n0 + i < N_NODES) deg[n0 + i] = c[i];
}

// ---------- Scan kernels: two-level exclusive scan over PADDED deg -> row_ptr ----------
__global__ void scan_partial(const int* __restrict__ deg, int* __restrict__ bsum) {
    __shared__ int red[256];
    const int t = threadIdx.x;
    const int base = blockIdx.x * SCAN_CHUNK;
    int s = 0;
    for (int i = t; i < SCAN_CHUNK; i += 256) {
        const int idx = base + i;
        if (idx < N_NODES) s += PAD16(deg[idx]);
    }
    red[t] = s;
    __syncthreads();
    for (int off = 128; off > 0; off >>= 1) {
        if (t < off) red[t] += red[t + off];
        __syncthreads();
    }
    if (t == 0) bsum[blockIdx.x] = red[0];
}

__global__ void scan_bsum(const int* __restrict__ bsum, int* __restrict__ boff,
                          int* __restrict__ row_ptr) {
    __shared__ int sh[256];
    const int t = threadIdx.x;
    const int v = (t < SCAN_BLOCKS) ? bsum[t] : 0;
    sh[t] = v;
    __syncthreads();
    for (int off = 1; off < 256; off <<= 1) {
        const int u = (t >= off) ? sh[t - off] : 0;
        __syncthreads();
        sh[t] += u;
        __syncthreads();
    }
    if (t < SCAN_BLOCKS) boff[t] = sh[t] - v;
    if (t == SCAN_BLOCKS - 1) row_ptr[N_NODES] = sh[t];  // padded total
}

__global__ void scan_apply(const int* __restrict__ deg, const int* __restrict__ boff,
                           int* __restrict__ row_ptr) {
    __shared__ int sh[256];
    const int t = threadIdx.x;
    const int base = blockIdx.x * SCAN_CHUNK;
    const int i0 = base + t * 2;
    const int d0p = (i0 < N_NODES) ? PAD16(deg[i0]) : 0;
    const int d1p = (i0 + 1 < N_NODES) ? PAD16(deg[i0 + 1]) : 0;
    const int tsum = d0p + d1p;
    sh[t] = tsum;
    __syncthreads();
    for (int off = 1; off < 256; off <<= 1) {
        const int u = (t >= off) ? sh[t - off] : 0;
        __syncthreads();
        sh[t] += u;
        __syncthreads();
    }
    const int texcl = sh[t] - tsum + boff[blockIdx.x];
    if (i0 < N_NODES) row_ptr[i0] = texcl;
    if (i0 + 1 < N_NODES) row_ptr[i0 + 1] = texcl + d0p;
}

// ---------- B2: per-bucket CSR fill in LDS, coalesced dump ----------
__global__ __launch_bounds__(1024) void col_fill(const int* __restrict__ Psrc,
                                                 const unsigned short* __restrict__ Pdl,
                                                 const int* __restrict__ bstart,
                                                 const int* __restrict__ row_ptr,
                                                 int* __restrict__ col) {
    __shared__ int buf[SEGCAP];    // 64 KB
    __shared__ int rp[BSZ + 1];
    __shared__ int cnt[BSZ];
    const int k = blockIdx.x;
    const int n0 = k * BSZ;
    const int nEnd = min(N_NODES, n0 + BSZ);
    const int nn = nEnd - n0;
    for (int i = threadIdx.x; i <= nn; i += 1024) rp[i] = row_ptr[n0 + i];
    for (int i = threadIdx.x; i < nn; i += 1024) cnt[i] = 0;
    __syncthreads();
    const int segbase = rp[0];
    const int seglen = rp[nn] - segbase;           // multiple of 16
    for (int i = threadIdx.x; i < seglen; i += 1024) buf[i] = N_NODES;  // pad = zero row
    __syncthreads();
    const int s = bstart[k], e = bstart[k + 1];
    for (int i = s + threadIdx.x; i < e; i += 1024) {
        const int dl = Pdl[i];
        const int r = atomicAdd(&cnt[dl], 1);
        buf[rp[dl] - segbase + r] = Psrc[i];
    }
    __syncthreads();
    for (int i = threadIdx.x; i < (seglen >> 2); i += 1024)
        ((int4*)(col + segbase))[i] = ((const int4*)buf)[i];
}

// ---------- Kernel 5: gather-aggregate, branchless 16-edge groups ----------
__global__ __launch_bounds__(256) void aggregate_kernel(
    const ushort* __restrict__ sup,
    const int* __restrict__ row_ptr,
    const int* __restrict__ degv,
    const int* __restrict__ col,
    const float* __restrict__ b,
    float* __restrict__ out) {
    const int wid = threadIdx.x >> 6;
    const int lane = threadIdx.x & 63;
    const int node = blockIdx.x * 4 + wid;
    if (node >= N_NODES) return;

    const int rs = lane >> 4;   // row slot 0..3
    const int fq = lane & 15;   // feature quad

    const int beg = row_ptr[node];
    const int end = row_ptr[node + 1];   // padded: (end-beg) % 16 == 0

    const uint4* sp = (const uint4*)sup;

    float acc[8] = {};
    for (int base = beg; base < end; base += 64) {
        const int rem = end - base;
        const int m = rem < 64 ? rem : 64;                 // in {16,32,48,64}
        const int mycol = (lane < m) ? col[base + lane] : 0;
        const int ng = m >> 4;
        for (int g = 0; g < ng; ++g) {
            uint4 v[4];
#pragma unroll
            for (int q = 0; q < 4; ++q) {
                const int s = __shfl(mycol, g * 16 + q * 4 + rs);
                v[q] = sp[(long long)s * 16 + fq];         // pads read zero row
            }
#pragma unroll
            for (int q = 0; q < 4; ++q) {
                acc[0] += blo(v[q].x); acc[1] += bhi(v[q].x);
                acc[2] += blo(v[q].y); acc[3] += bhi(v[q].y);
                acc[4] += blo(v[q].z); acc[5] += bhi(v[q].z);
                acc[6] += blo(v[q].w); acc[7] += bhi(v[q].w);
            }
        }
    }
    // reduce across the 4 row slots FIRST...
#pragma unroll
    for (int i = 0; i < 8; ++i) {
        acc[i] += __shfl_xor(acc[i], 16);
        acc[i] += __shfl_xor(acc[i], 32);
    }
    // ...THEN add self-loop exactly once
    {
        const uint4 v = sp[(long long)node * 16 + fq];
        acc[0] += blo(v.x); acc[1] += bhi(v.x);
        acc[2] += blo(v.y); acc[3] += bhi(v.y);
        acc[4] += blo(v.z); acc[5] += bhi(v.z);
        acc[6] += blo(v.w); acc[7] += bhi(v.w);
    }
    const float inv = 1.0f / (float)(degv[node] + 1);      // REAL degree for the mean
    const float4 b0 = ((const float4*)b)[fq * 2];
    const float4 b1 = ((const float4*)b)[fq * 2 + 1];
    if (rs == 0) {
        float4 r0, r1;
        r0.x = acc[0] * inv + b0.x; r0.y = acc[1] * inv + b0.y;
        r0.z = acc[2] * inv + b0.z; r0.w = acc[3] * inv + b0.w;
        r1.x = acc[4] * inv + b1.x; r1.y = acc[5] * inv + b1.y;
        r1.z = acc[6] * inv + b1.z; r1.w = acc[7] * inv + b1.w;
        float4* o4 = (float4*)out;
        o4[(long long)node * 32 + fq * 2] = r0;
        o4[(long long)node * 32 + fq * 2 + 1] = r1;
    }
}

extern "C" void kernel_launch(void* const* d_in, const int* in_sizes, int n_in,
                              void* d_out, int out_size, void* d_ws, size_t ws_size,
                              hipStream_t stream) {
    const float* x = (const float*)d_in[0];
    const int* src = (const int*)d_in[1];
    const int* dst = (const int*)d_in[2];
    const float* w = (const float*)d_in[3];
    const float* b = (const float*)d_in[4];
    float* out = (float*)d_out;

    // Workspace (~49 MB): sup 25.6 | deg .4 | row_ptr .4 | col 12.4 | Psrc 6.4 | Pdl 3.2 | C/O .5
    char* p = (char*)d_ws;
    ushort* sup = (ushort*)p;    p += (((size_t)(N_NODES + 1)) * F * sizeof(ushort) + 15) & ~15ULL;
    int* deg = (int*)p;          p += ((size_t)N_NODES * sizeof(int) + 15) & ~15ULL;
    int* row_ptr = (int*)p;      p += (((size_t)N_NODES + 1) * sizeof(int) + 15) & ~15ULL;
    int* col = (int*)p;          p += ((size_t)(NE + 15 * N_NODES) * sizeof(int) + 15) & ~15ULL;
    int* Psrc = (int*)p;         p += ((size_t)NE * sizeof(int) + 15) & ~15ULL;
    unsigned short* Pdl = (unsigned short*)p;  p += ((size_t)NE * sizeof(unsigned short) + 15) & ~15ULL;
    int* C = (int*)p;            p += ((size_t)NBUCK * NBUCK * sizeof(int) + 15) & ~15ULL;
    int* O = (int*)p;            p += ((size_t)NBUCK * NBUCK * sizeof(int) + 15) & ~15ULL;
    int* colsum = (int*)p;       p += ((size_t)NBUCK * sizeof(int) + 15) & ~15ULL;
    int* bstart = (int*)p;       p += (((size_t)NBUCK + 1) * sizeof(int) + 15) & ~15ULL;
    int* bsum = (int*)p;         p += ((size_t)SCAN_BLOCKS * sizeof(int) + 15) & ~15ULL;
    int* boff = (int*)p;

    // zero row at index N_NODES (pad gathers read it)
    hipMemsetAsync(sup + (size_t)N_NODES * F, 0, F * sizeof(ushort), stream);

    gemm_mfma<<<(N_NODES + 127) / 128, 256, 0, stream>>>(x, w, sup);
    bucket_hist<<<NBUCK, 1024, 0, stream>>>(dst, C);
    bucket_scan_cols<<<NBUCK, NBUCK, 0, stream>>>(C, O, colsum);
    bucket_scan_tot<<<1, NBUCK, 0, stream>>>(colsum, bstart);
    bucket_scatter<<<NBUCK, 1024, 0, stream>>>(src, dst, O, bstart, Psrc, Pdl);
    deg_hist<<<NBUCK, 256, 0, stream>>>(Pdl, bstart, deg);
    scan_partial<<<SCAN_BLOCKS, 256, 0, stream>>>(deg, bsum);
    scan_bsum<<<1, 256, 0, stream>>>(bsum, boff, row_ptr);
    scan_apply<<<SCAN_BLOCKS, 256, 0, stream>>>(deg, boff, row_ptr);
    col_fill<<<NBUCK, 1024, 0, stream>>>(Psrc, Pdl, bstart, row_ptr, col);
    aggregate_kernel<<<(N_NODES + 3) / 4, 256, 0, stream>>>(sup, row_ptr, deg, col, b, out);
}

// Round 13
// 135.980 us; speedup vs baseline: 1.3276x; 1.0503x over previous
//
#include <hip/hip_runtime.h>

#define N_NODES 100000
#define F 128
#define NE 1600000
#define NBUCK 256
#define BSZ 391                    // nodes per bucket; 391*256 = 100096 >= N
#define CHUNK2 (NE / NBUCK)        // 6250 edges per partition chunk
#define SEGCAP 16384               // LDS col-segment capacity (worst ~9.6K padded)
#define PAD8(v) (((v) + 7) & ~7)

typedef __attribute__((ext_vector_type(8))) short bf16x8;
typedef __attribute__((ext_vector_type(4))) float f32x4;

// fp32 -> bf16 round-to-nearest-even
__device__ __forceinline__ unsigned short f2bf(float f) {
    unsigned int u = __float_as_uint(f);
    return (unsigned short)((u + 0x7FFFu + ((u >> 16) & 1u)) >> 16);
}
__device__ __forceinline__ float blo(unsigned int v) { return __uint_as_float(v << 16); }
__device__ __forceinline__ float bhi(unsigned int v) { return __uint_as_float(v & 0xFFFF0000u); }

// ---------- Kernel 1: support(bf16) = x @ W via MFMA. 128x128 tile, 4 waves ----------
__global__ __launch_bounds__(256) void gemm_mfma(const float* __restrict__ x,
                                                 const float* __restrict__ w,
                                                 ushort* __restrict__ sup) {
    __shared__ ushort xs[128 * 128];   // 32 KB  [m][k]
    __shared__ ushort wt[128 * 128];   // 32 KB  [n][k]  (W transposed)
    const int t = threadIdx.x;
    const int rbase = blockIdx.x * 128;

#pragma unroll
    for (int it = 0; it < 16; ++it) {
        const int f = it * 256 + t;
        const int c = f & 127;
        const int kq = f >> 7;
        ushort4 o;
        o.x = f2bf(w[(4 * kq + 0) * F + c]);
        o.y = f2bf(w[(4 * kq + 1) * F + c]);
        o.z = f2bf(w[(4 * kq + 2) * F + c]);
        o.w = f2bf(w[(4 * kq + 3) * F + c]);
        ((ushort4*)wt)[c * 32 + (kq ^ ((c & 15) << 1))] = o;
    }
#pragma unroll
    for (int it = 0; it < 16; ++it) {
        const int f = it * 256 + t;
        const int r = f >> 5;
        const int cg = f & 31;
        const int gr = rbase + r;
        float4 v = make_float4(0.f, 0.f, 0.f, 0.f);
        if (gr < N_NODES) v = ((const float4*)x)[(long long)gr * 32 + cg];
        ushort4 o;
        o.x = f2bf(v.x); o.y = f2bf(v.y); o.z = f2bf(v.z); o.w = f2bf(v.w);
        ((ushort4*)xs)[r * 32 + (cg ^ ((r & 15) << 1))] = o;
    }
    __syncthreads();

    const int wid = t >> 6;
    const int lane = t & 63;
    const int wr = wid >> 1;
    const int wc = wid & 1;
    const int l16 = lane & 15;
    const int kg = lane >> 4;

    f32x4 acc[4][4] = {};
    const bf16x8* xs8 = (const bf16x8*)xs;
    const bf16x8* wt8 = (const bf16x8*)wt;

#pragma unroll
    for (int ks = 0; ks < 4; ++ks) {
        const int k8 = ks * 4 + kg;
        bf16x8 a[4], bb[4];
#pragma unroll
        for (int mi = 0; mi < 4; ++mi) {
            const int r = wr * 64 + mi * 16 + l16;
            a[mi] = xs8[r * 16 + (k8 ^ (r & 15))];
        }
#pragma unroll
        for (int ni = 0; ni < 4; ++ni) {
            const int c = wc * 64 + ni * 16 + l16;
            bb[ni] = wt8[c * 16 + (k8 ^ (c & 15))];
        }
#pragma unroll
        for (int mi = 0; mi < 4; ++mi)
#pragma unroll
            for (int ni = 0; ni < 4; ++ni)
                acc[mi][ni] = __builtin_amdgcn_mfma_f32_16x16x32_bf16(
                    a[mi], bb[ni], acc[mi][ni], 0, 0, 0);
    }

#pragma unroll
    for (int mi = 0; mi < 4; ++mi) {
#pragma unroll
        for (int reg = 0; reg < 4; ++reg) {
            const int r = rbase + wr * 64 + mi * 16 + kg * 4 + reg;
            if (r < N_NODES) {
#pragma unroll
                for (int ni = 0; ni < 4; ++ni) {
                    const int c = wc * 64 + ni * 16 + l16;
                    sup[(long long)r * F + c] = f2bf(acc[mi][ni][reg]);
                }
            }
        }
    }
}

// ---------- A1: per-chunk bucket histogram (256 bins, 1 KB LDS) ----------
__global__ __launch_bounds__(1024) void bucket_hist(const int* __restrict__ dst,
                                                    int* __restrict__ C) {
    __shared__ int cnt[NBUCK];
    if (threadIdx.x < NBUCK) cnt[threadIdx.x] = 0;
    __syncthreads();
    const int e0 = blockIdx.x * CHUNK2;
    for (int i = threadIdx.x; i < CHUNK2; i += 1024)
        atomicAdd(&cnt[dst[e0 + i] / BSZ], 1);
    __syncthreads();
    if (threadIdx.x < NBUCK) C[blockIdx.x * NBUCK + threadIdx.x] = cnt[threadIdx.x];
}

// ---------- A2a: per-bucket column scan over chunks (256 blocks, parallel) ----------
__global__ __launch_bounds__(NBUCK) void bucket_scan_cols(const int* __restrict__ C,
                                                          int* __restrict__ O,
                                                          int* __restrict__ colsum) {
    __shared__ int sh[NBUCK];
    const int k = blockIdx.x;    // bucket
    const int b = threadIdx.x;   // chunk
    const int v = C[b * NBUCK + k];
    sh[b] = v;
    __syncthreads();
    for (int off = 1; off < NBUCK; off <<= 1) {
        const int u = (b >= off) ? sh[b - off] : 0;
        __syncthreads();
        sh[b] += u;
        __syncthreads();
    }
    O[b * NBUCK + k] = sh[b] - v;            // exclusive prefix within bucket
    if (b == NBUCK - 1) colsum[k] = sh[b];   // bucket total
}

// ---------- A2b: scan bucket totals -> bstart (tiny single block) ----------
__global__ __launch_bounds__(NBUCK) void bucket_scan_tot(const int* __restrict__ colsum,
                                                         int* __restrict__ bstart) {
    __shared__ int sh[NBUCK];
    const int t = threadIdx.x;
    const int v = colsum[t];
    sh[t] = v;
    __syncthreads();
    for (int off = 1; off < NBUCK; off <<= 1) {
        const int u = (t >= off) ? sh[t - off] : 0;
        __syncthreads();
        sh[t] += u;
        __syncthreads();
    }
    bstart[t] = sh[t] - v;
    if (t == NBUCK - 1) bstart[NBUCK] = sh[t];
}

// ---------- A3: partition edges into buckets ----------
__global__ __launch_bounds__(1024) void bucket_scatter(const int* __restrict__ src,
                                                       const int* __restrict__ dst,
                                                       const int* __restrict__ O,
                                                       const int* __restrict__ bstart,
                                                       int* __restrict__ Psrc,
                                                       unsigned short* __restrict__ Pdl) {
    __shared__ int off[NBUCK];
    __shared__ int cnt[NBUCK];
    if (threadIdx.x < NBUCK) {
        off[threadIdx.x] = O[blockIdx.x * NBUCK + threadIdx.x] + bstart[threadIdx.x];
        cnt[threadIdx.x] = 0;
    }
    __syncthreads();
    const int e0 = blockIdx.x * CHUNK2;
    for (int i = threadIdx.x; i < CHUNK2; i += 1024) {
        const int d = dst[e0 + i];
        const int k = d / BSZ;
        const int r = atomicAdd(&cnt[k], 1);
        const int pos = off[k] + r;
        Psrc[pos] = src[e0 + i];
        Pdl[pos] = (unsigned short)(d - k * BSZ);
    }
}

// ---------- B1: per-bucket degree histogram -> deg (coalesced) + padded bucket sum ----------
__global__ __launch_bounds__(512) void deg_hist(const unsigned short* __restrict__ Pdl,
                                                const int* __restrict__ bstart,
                                                int* __restrict__ deg,
                                                int* __restrict__ pbsum) {
    __shared__ int c[BSZ];
    __shared__ int red[512];
    const int k = blockIdx.x;
    const int t = threadIdx.x;
    for (int i = t; i < BSZ; i += 512) c[i] = 0;
    __syncthreads();
    const int s = bstart[k], e = bstart[k + 1];
    for (int i = s + t; i < e; i += 512) atomicAdd(&c[Pdl[i]], 1);
    __syncthreads();
    const int n0 = k * BSZ;
    const int nn = min(N_NODES - n0, BSZ);
    int ps = 0;
    for (int i = t; i < BSZ; i += 512) {
        if (i < nn) { deg[n0 + i] = c[i]; ps += PAD8(c[i]); }
    }
    red[t] = ps;
    __syncthreads();
    for (int off = 256; off > 0; off >>= 1) {
        if (t < off) red[t] += red[t + off];
        __syncthreads();
    }
    if (t == 0) pbsum[k] = red[0];
}

// ---------- B1b: exclusive scan of 256 padded bucket sums -> pbase ----------
__global__ __launch_bounds__(NBUCK) void pb_scan(const int* __restrict__ pbsum,
                                                 int* __restrict__ pbase) {
    __shared__ int sh[NBUCK];
    const int t = threadIdx.x;
    const int v = pbsum[t];
    sh[t] = v;
    __syncthreads();
    for (int off = 1; off < NBUCK; off <<= 1) {
        const int u = (t >= off) ? sh[t - off] : 0;
        __syncthreads();
        sh[t] += u;
        __syncthreads();
    }
    pbase[t] = sh[t] - v;
    if (t == NBUCK - 1) pbase[NBUCK] = sh[t];
}

// ---------- B2: per-bucket CSR fill in LDS; derives row_ptr locally; coalesced dump ----------
__global__ __launch_bounds__(1024) void col_fill(const int* __restrict__ Psrc,
                                                 const unsigned short* __restrict__ Pdl,
                                                 const int* __restrict__ bstart,
                                                 const int* __restrict__ pbase,
                                                 const int* __restrict__ deg,
                                                 int* __restrict__ row_ptr,
                                                 int* __restrict__ col) {
    __shared__ int buf[SEGCAP];    // 64 KB
    __shared__ int sh[512];
    __shared__ int rp[BSZ + 1];
    __shared__ int cnt[BSZ];
    const int k = blockIdx.x;
    const int n0 = k * BSZ;
    const int nn = min(N_NODES - n0, BSZ);
    const int t = threadIdx.x;
    int myp = 0;
    if (t < 512) {
        myp = (t < nn) ? PAD8(deg[n0 + t]) : 0;
        sh[t] = myp;
    }
    if (t < BSZ) cnt[t] = 0;
    __syncthreads();
    // inclusive scan over 512 padded degrees
    for (int off = 1; off < 512; off <<= 1) {
        int u = 0;
        if (t < 512 && t >= off) u = sh[t - off];
        __syncthreads();
        if (t < 512) sh[t] += u;
        __syncthreads();
    }
    const int base = pbase[k];
    if (t == 0) rp[0] = base;
    if (t < nn) rp[t + 1] = base + sh[t];
    __syncthreads();
    // write row_ptr (coalesced)
    for (int i = t; i < nn; i += 1024) row_ptr[n0 + i] = rp[i];
    if (k == NBUCK - 1 && t == 0) row_ptr[N_NODES] = rp[nn];
    const int segbase = rp[0];
    const int seglen = rp[nn] - segbase;             // multiple of 8
    for (int i = t; i < seglen; i += 1024) buf[i] = N_NODES;  // pad = zero row
    __syncthreads();
    const int s = bstart[k], e = bstart[k + 1];
    for (int i = s + t; i < e; i += 1024) {
        const int dl = Pdl[i];
        const int r = atomicAdd(&cnt[dl], 1);
        buf[rp[dl] - segbase + r] = Psrc[i];
    }
    __syncthreads();
    for (int i = t; i < (seglen >> 2); i += 1024)
        ((int4*)(col + segbase))[i] = ((const int4*)buf)[i];
}

// ---------- Kernel 5: gather-aggregate, branchless, PAD8 (16-groups + 8-tail) ----------
__global__ __launch_bounds__(256) void aggregate_kernel(
    const ushort* __restrict__ sup,
    const int* __restrict__ row_ptr,
    const int* __restrict__ degv,
    const int* __restrict__ col,
    const float* __restrict__ b,
    float* __restrict__ out) {
    const int wid = threadIdx.x >> 6;
    const int lane = threadIdx.x & 63;
    const int node = blockIdx.x * 4 + wid;
    if (node >= N_NODES) return;

    const int rs = lane >> 4;   // row slot 0..3
    const int fq = lane & 15;   // feature quad

    const int beg = row_ptr[node];
    const int end = row_ptr[node + 1];   // padded: (end-beg) % 8 == 0

    const uint4* sp = (const uint4*)sup;

    float acc[8] = {};
    for (int base = beg; base < end; base += 64) {
        const int rem = end - base;
        const int m = rem < 64 ? rem : 64;                 // multiple of 8
        const int mycol = (lane < m) ? col[base + lane] : 0;
        const int ng16 = m >> 4;
        for (int g = 0; g < ng16; ++g) {
            uint4 v[4];
#pragma unroll
            for (int q = 0; q < 4; ++q) {
                const int s = __shfl(mycol, g * 16 + q * 4 + rs);
                v[q] = sp[(long long)s * 16 + fq];         // pads read zero row
            }
#pragma unroll
            for (int q = 0; q < 4; ++q) {
                acc[0] += blo(v[q].x); acc[1] += bhi(v[q].x);
                acc[2] += blo(v[q].y); acc[3] += bhi(v[q].y);
                acc[4] += blo(v[q].z); acc[5] += bhi(v[q].z);
                acc[6] += blo(v[q].w); acc[7] += bhi(v[q].w);
            }
        }
        if (m & 8) {                                       // 8-edge tail group
            uint4 v[2];
#pragma unroll
            for (int q = 0; q < 2; ++q) {
                const int s = __shfl(mycol, (ng16 << 4) + q * 4 + rs);
                v[q] = sp[(long long)s * 16 + fq];
            }
#pragma unroll
            for (int q = 0; q < 2; ++q) {
                acc[0] += blo(v[q].x); acc[1] += bhi(v[q].x);
                acc[2] += blo(v[q].y); acc[3] += bhi(v[q].y);
                acc[4] += blo(v[q].z); acc[5] += bhi(v[q].z);
                acc[6] += blo(v[q].w); acc[7] += bhi(v[q].w);
            }
        }
    }
    // reduce across the 4 row slots FIRST...
#pragma unroll
    for (int i = 0; i < 8; ++i) {
        acc[i] += __shfl_xor(acc[i], 16);
        acc[i] += __shfl_xor(acc[i], 32);
    }
    // ...THEN add self-loop exactly once
    {
        const uint4 v = sp[(long long)node * 16 + fq];
        acc[0] += blo(v.x); acc[1] += bhi(v.x);
        acc[2] += blo(v.y); acc[3] += bhi(v.y);
        acc[4] += blo(v.z); acc[5] += bhi(v.z);
        acc[6] += blo(v.w); acc[7] += bhi(v.w);
    }
    const float inv = 1.0f / (float)(degv[node] + 1);      // REAL degree for the mean
    const float4 b0 = ((const float4*)b)[fq * 2];
    const float4 b1 = ((const float4*)b)[fq * 2 + 1];
    if (rs == 0) {
        float4 r0, r1;
        r0.x = acc[0] * inv + b0.x; r0.y = acc[1] * inv + b0.y;
        r0.z = acc[2] * inv + b0.z; r0.w = acc[3] * inv + b0.w;
        r1.x = acc[4] * inv + b1.x; r1.y = acc[5] * inv + b1.y;
        r1.z = acc[6] * inv + b1.z; r1.w = acc[7] * inv + b1.w;
        float4* o4 = (float4*)out;
        o4[(long long)node * 32 + fq * 2] = r0;
        o4[(long long)node * 32 + fq * 2 + 1] = r1;
    }
}

extern "C" void kernel_launch(void* const* d_in, const int* in_sizes, int n_in,
                              void* d_out, int out_size, void* d_ws, size_t ws_size,
                              hipStream_t stream) {
    const float* x = (const float*)d_in[0];
    const int* src = (const int*)d_in[1];
    const int* dst = (const int*)d_in[2];
    const float* w = (const float*)d_in[3];
    const float* b = (const float*)d_in[4];
    float* out = (float*)d_out;

    // Workspace (~46 MB): sup 25.6 | deg .4 | row_ptr .4 | col 9.2 | Psrc 6.4 | Pdl 3.2 | small
    char* p = (char*)d_ws;
    ushort* sup = (ushort*)p;    p += (((size_t)(N_NODES + 1)) * F * sizeof(ushort) + 15) & ~15ULL;
    int* deg = (int*)p;          p += ((size_t)N_NODES * sizeof(int) + 15) & ~15ULL;
    int* row_ptr = (int*)p;      p += (((size_t)N_NODES + 1) * sizeof(int) + 15) & ~15ULL;
    int* col = (int*)p;          p += ((size_t)(NE + 7 * N_NODES) * sizeof(int) + 15) & ~15ULL;
    int* Psrc = (int*)p;         p += ((size_t)NE * sizeof(int) + 15) & ~15ULL;
    unsigned short* Pdl = (unsigned short*)p;  p += ((size_t)NE * sizeof(unsigned short) + 15) & ~15ULL;
    int* C = (int*)p;            p += ((size_t)NBUCK * NBUCK * sizeof(int) + 15) & ~15ULL;
    int* O = (int*)p;            p += ((size_t)NBUCK * NBUCK * sizeof(int) + 15) & ~15ULL;
    int* colsum = (int*)p;       p += ((size_t)NBUCK * sizeof(int) + 15) & ~15ULL;
    int* bstart = (int*)p;       p += (((size_t)NBUCK + 1) * sizeof(int) + 15) & ~15ULL;
    int* pbsum = (int*)p;        p += ((size_t)NBUCK * sizeof(int) + 15) & ~15ULL;
    int* pbase = (int*)p;

    // zero row at index N_NODES (pad gathers read it)
    hipMemsetAsync(sup + (size_t)N_NODES * F, 0, F * sizeof(ushort), stream);

    gemm_mfma<<<(N_NODES + 127) / 128, 256, 0, stream>>>(x, w, sup);
    bucket_hist<<<NBUCK, 1024, 0, stream>>>(dst, C);
    bucket_scan_cols<<<NBUCK, NBUCK, 0, stream>>>(C, O, colsum);
    bucket_scan_tot<<<1, NBUCK, 0, stream>>>(colsum, bstart);
    bucket_scatter<<<NBUCK, 1024, 0, stream>>>(src, dst, O, bstart, Psrc, Pdl);
    deg_hist<<<NBUCK, 512, 0, stream>>>(Pdl, bstart, deg, pbsum);
    pb_scan<<<1, NBUCK, 0, stream>>>(pbsum, pbase);
    col_fill<<<NBUCK, 1024, 0, stream>>>(Psrc, Pdl, bstart, pbase, deg, row_ptr, col);
    aggregate_kernel<<<(N_NODES + 3) / 4, 256, 0, stream>>>(sup, row_ptr, deg, col, b, out);
}

// Round 14
// 134.726 us; speedup vs baseline: 1.3400x; 1.0093x over previous
//
#include <hip/hip_runtime.h>

#define N_NODES 100000
#define F 128
#define NE 1600000
#define NBUCK 256
#define BSZ 391                    // nodes per bucket; 391*256 = 100096 >= N
#define CHUNK2 (NE / NBUCK)        // 6250 edges per partition chunk
#define CAP 8192                   // per-bucket region capacity (mean 6256, +24 sigma)
#define SEGCAP 16384               // LDS col-segment capacity (worst ~8K padded)
#define PAD8(v) (((v) + 7) & ~7)

typedef __attribute__((ext_vector_type(8))) short bf16x8;
typedef __attribute__((ext_vector_type(4))) float f32x4;

// fp32 -> bf16 round-to-nearest-even
__device__ __forceinline__ unsigned short f2bf(float f) {
    unsigned int u = __float_as_uint(f);
    return (unsigned short)((u + 0x7FFFu + ((u >> 16) & 1u)) >> 16);
}
__device__ __forceinline__ float blo(unsigned int v) { return __uint_as_float(v << 16); }
__device__ __forceinline__ float bhi(unsigned int v) { return __uint_as_float(v & 0xFFFF0000u); }

// ---------- Kernel 1: support(bf16) = x @ W via MFMA. 128x128 tile, 4 waves ----------
__global__ __launch_bounds__(256) void gemm_mfma(const float* __restrict__ x,
                                                 const float* __restrict__ w,
                                                 ushort* __restrict__ sup) {
    __shared__ ushort xs[128 * 128];   // 32 KB  [m][k]
    __shared__ ushort wt[128 * 128];   // 32 KB  [n][k]  (W transposed)
    const int t = threadIdx.x;
    const int rbase = blockIdx.x * 128;

#pragma unroll
    for (int it = 0; it < 16; ++it) {
        const int f = it * 256 + t;
        const int c = f & 127;
        const int kq = f >> 7;
        ushort4 o;
        o.x = f2bf(w[(4 * kq + 0) * F + c]);
        o.y = f2bf(w[(4 * kq + 1) * F + c]);
        o.z = f2bf(w[(4 * kq + 2) * F + c]);
        o.w = f2bf(w[(4 * kq + 3) * F + c]);
        ((ushort4*)wt)[c * 32 + (kq ^ ((c & 15) << 1))] = o;
    }
#pragma unroll
    for (int it = 0; it < 16; ++it) {
        const int f = it * 256 + t;
        const int r = f >> 5;
        const int cg = f & 31;
        const int gr = rbase + r;
        float4 v = make_float4(0.f, 0.f, 0.f, 0.f);
        if (gr < N_NODES) v = ((const float4*)x)[(long long)gr * 32 + cg];
        ushort4 o;
        o.x = f2bf(v.x); o.y = f2bf(v.y); o.z = f2bf(v.z); o.w = f2bf(v.w);
        ((ushort4*)xs)[r * 32 + (cg ^ ((r & 15) << 1))] = o;
    }
    __syncthreads();

    const int wid = t >> 6;
    const int lane = t & 63;
    const int wr = wid >> 1;
    const int wc = wid & 1;
    const int l16 = lane & 15;
    const int kg = lane >> 4;

    f32x4 acc[4][4] = {};
    const bf16x8* xs8 = (const bf16x8*)xs;
    const bf16x8* wt8 = (const bf16x8*)wt;

#pragma unroll
    for (int ks = 0; ks < 4; ++ks) {
        const int k8 = ks * 4 + kg;
        bf16x8 a[4], bb[4];
#pragma unroll
        for (int mi = 0; mi < 4; ++mi) {
            const int r = wr * 64 + mi * 16 + l16;
            a[mi] = xs8[r * 16 + (k8 ^ (r & 15))];
        }
#pragma unroll
        for (int ni = 0; ni < 4; ++ni) {
            const int c = wc * 64 + ni * 16 + l16;
            bb[ni] = wt8[c * 16 + (k8 ^ (c & 15))];
        }
#pragma unroll
        for (int mi = 0; mi < 4; ++mi)
#pragma unroll
            for (int ni = 0; ni < 4; ++ni)
                acc[mi][ni] = __builtin_amdgcn_mfma_f32_16x16x32_bf16(
                    a[mi], bb[ni], acc[mi][ni], 0, 0, 0);
    }

#pragma unroll
    for (int mi = 0; mi < 4; ++mi) {
#pragma unroll
        for (int reg = 0; reg < 4; ++reg) {
            const int r = rbase + wr * 64 + mi * 16 + kg * 4 + reg;
            if (r < N_NODES) {
#pragma unroll
                for (int ni = 0; ni < 4; ++ni) {
                    const int c = wc * 64 + ni * 16 + l16;
                    sup[(long long)r * F + c] = f2bf(acc[mi][ni][reg]);
                }
            }
        }
    }
}

// ---------- A: partition edges into per-bucket regions via global bump allocator ----------
__global__ __launch_bounds__(1024) void bucket_scatter2(const int* __restrict__ src,
                                                        const int* __restrict__ dst,
                                                        int* __restrict__ gcnt,
                                                        int* __restrict__ Psrc,
                                                        unsigned short* __restrict__ Pdl) {
    __shared__ int hist[NBUCK];
    __shared__ int off[NBUCK];
    __shared__ int pos[NBUCK];
    const int t = threadIdx.x;
    if (t < NBUCK) { hist[t] = 0; pos[t] = 0; }
    __syncthreads();
    const int e0 = blockIdx.x * CHUNK2;
    for (int i = t; i < CHUNK2; i += 1024)
        atomicAdd(&hist[dst[e0 + i] / BSZ], 1);
    __syncthreads();
    if (t < NBUCK) off[t] = atomicAdd(&gcnt[t], hist[t]);   // reserve contiguous run
    __syncthreads();
    for (int i = t; i < CHUNK2; i += 1024) {
        const int d = dst[e0 + i];
        const int k = d / BSZ;
        const int r = atomicAdd(&pos[k], 1);
        const int p = k * CAP + off[k] + r;
        Psrc[p] = src[e0 + i];
        Pdl[p] = (unsigned short)(d - k * BSZ);
    }
}

// ---------- B: per-bucket deg count + local padded scan + bump-allocated CSR fill ----------
__global__ __launch_bounds__(1024) void col_fill2(const int* __restrict__ Psrc,
                                                  const unsigned short* __restrict__ Pdl,
                                                  const int* __restrict__ gcnt,
                                                  int* __restrict__ segalloc,
                                                  int* __restrict__ deg,
                                                  int* __restrict__ row_ptr,
                                                  int* __restrict__ col) {
    __shared__ int buf[SEGCAP];    // 64 KB
    __shared__ int c[BSZ];         // degree counts
    __shared__ int cnt[BSZ];       // rank counters
    __shared__ int sh[512];        // scan
    __shared__ int rp[BSZ];        // absolute segment start per node
    __shared__ int segbase_s;
    const int k = blockIdx.x;
    const int t = threadIdx.x;
    const int n0 = k * BSZ;
    const int nn = min(N_NODES - n0, BSZ);
    for (int i = t; i < BSZ; i += 1024) { c[i] = 0; cnt[i] = 0; }
    __syncthreads();
    const int e0 = k * CAP;
    const int ne = gcnt[k];
    for (int i = t; i < ne; i += 1024) atomicAdd(&c[Pdl[e0 + i]], 1);
    __syncthreads();
    // inclusive scan of padded degrees over 512 slots (nn <= 391)
    int myp = 0;
    if (t < 512) { myp = (t < nn) ? PAD8(c[t]) : 0; sh[t] = myp; }
    __syncthreads();
    for (int off = 1; off < 512; off <<= 1) {
        int u = 0;
        if (t < 512 && t >= off) u = sh[t - off];
        __syncthreads();
        if (t < 512) sh[t] += u;
        __syncthreads();
    }
    if (t == 511) segbase_s = atomicAdd(segalloc, sh[511]);
    __syncthreads();
    const int segbase = segbase_s;
    const int seglen = sh[511];                   // multiple of 8
    if (t < nn) {
        const int start = segbase + sh[t] - myp;  // exclusive prefix
        rp[t] = start;
        row_ptr[n0 + t] = start;
        deg[n0 + t] = c[t];
    }
    __syncthreads();
    for (int i = t; i < seglen; i += 1024) buf[i] = N_NODES;   // pad = zero row
    __syncthreads();
    for (int i = t; i < ne; i += 1024) {
        const int dl = Pdl[e0 + i];
        const int r = atomicAdd(&cnt[dl], 1);
        buf[rp[dl] - segbase + r] = Psrc[e0 + i];
    }
    __syncthreads();
    for (int i = t; i < (seglen >> 2); i += 1024)
        ((int4*)(col + segbase))[i] = ((const int4*)buf)[i];
}

// ---------- Kernel 5: gather-aggregate, branchless; end derived from PAD8(deg) ----------
__global__ __launch_bounds__(256) void aggregate_kernel(
    const ushort* __restrict__ sup,
    const int* __restrict__ row_ptr,
    const int* __restrict__ degv,
    const int* __restrict__ col,
    const float* __restrict__ b,
    float* __restrict__ out) {
    const int wid = threadIdx.x >> 6;
    const int lane = threadIdx.x & 63;
    const int node = blockIdx.x * 4 + wid;
    if (node >= N_NODES) return;

    const int rs = lane >> 4;   // row slot 0..3
    const int fq = lane & 15;   // feature quad

    const int beg = row_ptr[node];
    const int dg = degv[node];
    const int end = beg + PAD8(dg);

    const uint4* sp = (const uint4*)sup;

    float acc[8] = {};
    for (int base = beg; base < end; base += 64) {
        const int rem = end - base;
        const int m = rem < 64 ? rem : 64;                 // multiple of 8
        const int mycol = (lane < m) ? col[base + lane] : 0;
        const int ng16 = m >> 4;
        for (int g = 0; g < ng16; ++g) {
            uint4 v[4];
#pragma unroll
            for (int q = 0; q < 4; ++q) {
                const int s = __shfl(mycol, g * 16 + q * 4 + rs);
                v[q] = sp[(long long)s * 16 + fq];         // pads read zero row
            }
#pragma unroll
            for (int q = 0; q < 4; ++q) {
                acc[0] += blo(v[q].x); acc[1] += bhi(v[q].x);
                acc[2] += blo(v[q].y); acc[3] += bhi(v[q].y);
                acc[4] += blo(v[q].z); acc[5] += bhi(v[q].z);
                acc[6] += blo(v[q].w); acc[7] += bhi(v[q].w);
            }
        }
        if (m & 8) {                                       // 8-edge tail group
            uint4 v[2];
#pragma unroll
            for (int q = 0; q < 2; ++q) {
                const int s = __shfl(mycol, (ng16 << 4) + q * 4 + rs);
                v[q] = sp[(long long)s * 16 + fq];
            }
#pragma unroll
            for (int q = 0; q < 2; ++q) {
                acc[0] += blo(v[q].x); acc[1] += bhi(v[q].x);
                acc[2] += blo(v[q].y); acc[3] += bhi(v[q].y);
                acc[4] += blo(v[q].z); acc[5] += bhi(v[q].z);
                acc[6] += blo(v[q].w); acc[7] += bhi(v[q].w);
            }
        }
    }
    // reduce across the 4 row slots FIRST...
#pragma unroll
    for (int i = 0; i < 8; ++i) {
        acc[i] += __shfl_xor(acc[i], 16);
        acc[i] += __shfl_xor(acc[i], 32);
    }
    // ...THEN add self-loop exactly once
    {
        const uint4 v = sp[(long long)node * 16 + fq];
        acc[0] += blo(v.x); acc[1] += bhi(v.x);
        acc[2] += blo(v.y); acc[3] += bhi(v.y);
        acc[4] += blo(v.z); acc[5] += bhi(v.z);
        acc[6] += blo(v.w); acc[7] += bhi(v.w);
    }
    const float inv = 1.0f / (float)(dg + 1);
    const float4 b0 = ((const float4*)b)[fq * 2];
    const float4 b1 = ((const float4*)b)[fq * 2 + 1];
    if (rs == 0) {
        float4 r0, r1;
        r0.x = acc[0] * inv + b0.x; r0.y = acc[1] * inv + b0.y;
        r0.z = acc[2] * inv + b0.z; r0.w = acc[3] * inv + b0.w;
        r1.x = acc[4] * inv + b1.x; r1.y = acc[5] * inv + b1.y;
        r1.z = acc[6] * inv + b1.z; r1.w = acc[7] * inv + b1.w;
        float4* o4 = (float4*)out;
        o4[(long long)node * 32 + fq * 2] = r0;
        o4[(long long)node * 32 + fq * 2 + 1] = r1;
    }
}

extern "C" void kernel_launch(void* const* d_in, const int* in_sizes, int n_in,
                              void* d_out, int out_size, void* d_ws, size_t ws_size,
                              hipStream_t stream) {
    const float* x = (const float*)d_in[0];
    const int* src = (const int*)d_in[1];
    const int* dst = (const int*)d_in[2];
    const float* w = (const float*)d_in[3];
    const float* b = (const float*)d_in[4];
    float* out = (float*)d_out;

    // Workspace (~49 MB): sup 25.6 | deg .4 | row_ptr .4 | col 9.2 | Psrc 8.4 | Pdl 4.2 | ctrs
    char* p = (char*)d_ws;
    ushort* sup = (ushort*)p;    p += (((size_t)(N_NODES + 1)) * F * sizeof(ushort) + 15) & ~15ULL;
    int* deg = (int*)p;          p += ((size_t)N_NODES * sizeof(int) + 15) & ~15ULL;
    int* row_ptr = (int*)p;      p += ((size_t)N_NODES * sizeof(int) + 15) & ~15ULL;
    int* col = (int*)p;          p += ((size_t)(NE + 7 * N_NODES) * sizeof(int) + 15) & ~15ULL;
    int* Psrc = (int*)p;         p += ((size_t)NBUCK * CAP * sizeof(int) + 15) & ~15ULL;
    unsigned short* Pdl = (unsigned short*)p;  p += ((size_t)NBUCK * CAP * sizeof(unsigned short) + 15) & ~15ULL;
    int* gcnt = (int*)p;         p += ((size_t)NBUCK * sizeof(int) + 15) & ~15ULL;
    int* segalloc = (int*)p;

    // zero allocator counters + the pad zero-row
    hipMemsetAsync(gcnt, 0, (NBUCK + 1) * sizeof(int), stream);   // gcnt is last before segalloc? no: separate
    hipMemsetAsync(segalloc, 0, sizeof(int), stream);
    hipMemsetAsync(sup + (size_t)N_NODES * F, 0, F * sizeof(ushort), stream);

    gemm_mfma<<<(N_NODES + 127) / 128, 256, 0, stream>>>(x, w, sup);
    bucket_scatter2<<<NBUCK, 1024, 0, stream>>>(src, dst, gcnt, Psrc, Pdl);
    col_fill2<<<NBUCK, 1024, 0, stream>>>(Psrc, Pdl, gcnt, segalloc, deg, row_ptr, col);
    aggregate_kernel<<<(N_NODES + 3) / 4, 256, 0, stream>>>(sup, row_ptr, deg, col, b, out);
}

// Round 15
// 130.439 us; speedup vs baseline: 1.3840x; 1.0329x over previous
//
#include <hip/hip_runtime.h>

#define N_NODES 100000
#define F 128
#define NE 1600000
#define NBUCK 256
#define BSZ 391                    // nodes per bucket; 391*256 = 100096 >= N
#define CHUNK2 (NE / NBUCK)        // 6250 edges per partition chunk
#define CAP 8192                   // per-bucket region capacity (mean 6256, +24 sigma)
#define SEGCAP 16384               // LDS col-segment capacity (worst ~8K padded)
#define PAD8(v) (((v) + 7) & ~7)

typedef __attribute__((ext_vector_type(8))) short bf16x8;
typedef __attribute__((ext_vector_type(4))) float f32x4;

// fp32 -> bf16 round-to-nearest-even
__device__ __forceinline__ unsigned short f2bf(float f) {
    unsigned int u = __float_as_uint(f);
    return (unsigned short)((u + 0x7FFFu + ((u >> 16) & 1u)) >> 16);
}
__device__ __forceinline__ float blo(unsigned int v) { return __uint_as_float(v << 16); }
__device__ __forceinline__ float bhi(unsigned int v) { return __uint_as_float(v & 0xFFFF0000u); }

// ---------- Kernel 0: one-time prep — swizzled bf16 W^T image + zero counters/pad row ----------
__global__ __launch_bounds__(256) void prep_w(const float* __restrict__ w,
                                              ushort* __restrict__ wimg,
                                              ushort* __restrict__ sup,
                                              int* __restrict__ gcnt,
                                              int* __restrict__ segalloc) {
    const int t = threadIdx.x;
#pragma unroll
    for (int it = 0; it < 16; ++it) {
        const int f = it * 256 + t;
        const int c = f & 127;
        const int kq = f >> 7;
        ushort4 o;
        o.x = f2bf(w[(4 * kq + 0) * F + c]);
        o.y = f2bf(w[(4 * kq + 1) * F + c]);
        o.z = f2bf(w[(4 * kq + 2) * F + c]);
        o.w = f2bf(w[(4 * kq + 3) * F + c]);
        ((ushort4*)wimg)[c * 32 + (kq ^ ((c & 15) << 1))] = o;
    }
    if (t < 128) sup[(size_t)N_NODES * F + t] = 0;   // zero pad row
    if (t < NBUCK) gcnt[t] = 0;
    if (t == 0) *segalloc = 0;
}

// ---------- Kernel 1: support(bf16) = x @ W via MFMA (swapped operands -> row-in-lane C) ----------
__global__ __launch_bounds__(256) void gemm_mfma(const float* __restrict__ x,
                                                 const ushort* __restrict__ wimg,
                                                 ushort* __restrict__ sup) {
    __shared__ ushort xs[128 * 128];   // 32 KB  [m][k] swizzled
    __shared__ ushort wt[128 * 128];   // 32 KB  pre-swizzled W^T image
    const int t = threadIdx.x;
    const int rbase = blockIdx.x * 128;

    // stage pre-built W image verbatim (no conversion)
#pragma unroll
    for (int i = 0; i < 8; ++i)
        ((float4*)wt)[i * 256 + t] = ((const float4*)wimg)[i * 256 + t];
    // stage x tile as bf16, swizzled
#pragma unroll
    for (int it = 0; it < 16; ++it) {
        const int f = it * 256 + t;
        const int r = f >> 5;
        const int cg = f & 31;
        const int gr = rbase + r;
        float4 v = make_float4(0.f, 0.f, 0.f, 0.f);
        if (gr < N_NODES) v = ((const float4*)x)[(long long)gr * 32 + cg];
        ushort4 o;
        o.x = f2bf(v.x); o.y = f2bf(v.y); o.z = f2bf(v.z); o.w = f2bf(v.w);
        ((ushort4*)xs)[r * 32 + (cg ^ ((r & 15) << 1))] = o;
    }
    __syncthreads();

    const int wid = t >> 6;
    const int lane = t & 63;
    const int wr = wid >> 1;
    const int wc = wid & 1;
    const int l16 = lane & 15;
    const int kg = lane >> 4;

    f32x4 acc[4][4] = {};
    const bf16x8* xs8 = (const bf16x8*)xs;
    const bf16x8* wt8 = (const bf16x8*)wt;

#pragma unroll
    for (int ks = 0; ks < 4; ++ks) {
        const int k8 = ks * 4 + kg;
        bf16x8 a[4], bb[4];
#pragma unroll
        for (int mi = 0; mi < 4; ++mi) {
            const int r = wr * 64 + mi * 16 + l16;
            a[mi] = xs8[r * 16 + (k8 ^ (r & 15))];
        }
#pragma unroll
        for (int ni = 0; ni < 4; ++ni) {
            const int c = wc * 64 + ni * 16 + l16;
            bb[ni] = wt8[c * 16 + (k8 ^ (c & 15))];
        }
        // swapped operands: D = (x-block . W-block)^T  ->  row in l16, cols in regs
#pragma unroll
        for (int mi = 0; mi < 4; ++mi)
#pragma unroll
            for (int ni = 0; ni < 4; ++ni)
                acc[mi][ni] = __builtin_amdgcn_mfma_f32_16x16x32_bf16(
                    bb[ni], a[mi], acc[mi][ni], 0, 0, 0);
    }

    // epilogue: thread holds rows r = wr*64+mi*16+l16, cols wc*64+ni*16+kg*4..+3
#pragma unroll
    for (int mi = 0; mi < 4; ++mi) {
        const int r = rbase + wr * 64 + mi * 16 + l16;
        if (r < N_NODES) {
#pragma unroll
            for (int ni = 0; ni < 4; ++ni) {
                ushort4 o;
                o.x = f2bf(acc[mi][ni][0]);
                o.y = f2bf(acc[mi][ni][1]);
                o.z = f2bf(acc[mi][ni][2]);
                o.w = f2bf(acc[mi][ni][3]);
                const long long idx = ((long long)r * F + wc * 64 + ni * 16 + kg * 4) >> 2;
                ((ushort4*)sup)[idx] = o;
            }
        }
    }
}

// ---------- A: partition edges into per-bucket regions via global bump allocator ----------
__global__ __launch_bounds__(1024) void bucket_scatter2(const int* __restrict__ src,
                                                        const int* __restrict__ dst,
                                                        int* __restrict__ gcnt,
                                                        int* __restrict__ Psrc,
                                                        unsigned short* __restrict__ Pdl) {
    __shared__ int hist[NBUCK];
    __shared__ int off[NBUCK];
    __shared__ int pos[NBUCK];
    const int t = threadIdx.x;
    if (t < NBUCK) { hist[t] = 0; pos[t] = 0; }
    __syncthreads();
    const int e0 = blockIdx.x * CHUNK2;
    for (int i = t; i < CHUNK2; i += 1024)
        atomicAdd(&hist[dst[e0 + i] / BSZ], 1);
    __syncthreads();
    if (t < NBUCK) off[t] = atomicAdd(&gcnt[t], hist[t]);   // reserve contiguous run
    __syncthreads();
    for (int i = t; i < CHUNK2; i += 1024) {
        const int d = dst[e0 + i];
        const int k = d / BSZ;
        const int r = atomicAdd(&pos[k], 1);
        const int p = k * CAP + off[k] + r;
        Psrc[p] = src[e0 + i];
        Pdl[p] = (unsigned short)(d - k * BSZ);
    }
}

// ---------- B: per-bucket deg count + local padded scan + bump-allocated CSR fill ----------
__global__ __launch_bounds__(1024) void col_fill2(const int* __restrict__ Psrc,
                                                  const unsigned short* __restrict__ Pdl,
                                                  const int* __restrict__ gcnt,
                                                  int* __restrict__ segalloc,
                                                  int* __restrict__ deg,
                                                  int* __restrict__ row_ptr,
                                                  int* __restrict__ col) {
    __shared__ int buf[SEGCAP];    // 64 KB
    __shared__ int c[BSZ];         // degree counts
    __shared__ int cnt[BSZ];       // rank counters
    __shared__ int sh[512];        // scan
    __shared__ int rp[BSZ];        // absolute segment start per node
    __shared__ int segbase_s;
    const int k = blockIdx.x;
    const int t = threadIdx.x;
    const int n0 = k * BSZ;
    const int nn = min(N_NODES - n0, BSZ);
    for (int i = t; i < BSZ; i += 1024) { c[i] = 0; cnt[i] = 0; }
    __syncthreads();
    const int e0 = k * CAP;
    const int ne = gcnt[k];
    for (int i = t; i < ne; i += 1024) atomicAdd(&c[Pdl[e0 + i]], 1);
    __syncthreads();
    // inclusive scan of padded degrees over 512 slots (nn <= 391)
    int myp = 0;
    if (t < 512) { myp = (t < nn) ? PAD8(c[t]) : 0; sh[t] = myp; }
    __syncthreads();
    for (int off = 1; off < 512; off <<= 1) {
        int u = 0;
        if (t < 512 && t >= off) u = sh[t - off];
        __syncthreads();
        if (t < 512) sh[t] += u;
        __syncthreads();
    }
    if (t == 511) segbase_s = atomicAdd(segalloc, sh[511]);
    __syncthreads();
    const int segbase = segbase_s;
    const int seglen = sh[511];                   // multiple of 8
    if (t < nn) {
        const int start = segbase + sh[t] - myp;  // exclusive prefix
        rp[t] = start;
        row_ptr[n0 + t] = start;
        deg[n0 + t] = c[t];
    }
    __syncthreads();
    for (int i = t; i < seglen; i += 1024) buf[i] = N_NODES;   // pad = zero row
    __syncthreads();
    for (int i = t; i < ne; i += 1024) {
        const int dl = Pdl[e0 + i];
        const int r = atomicAdd(&cnt[dl], 1);
        buf[rp[dl] - segbase + r] = Psrc[e0 + i];
    }
    __syncthreads();
    for (int i = t; i < (seglen >> 2); i += 1024)
        ((int4*)(col + segbase))[i] = ((const int4*)buf)[i];
}

// ---------- Kernel 5: gather-aggregate, branchless; end derived from PAD8(deg) ----------
__global__ __launch_bounds__(256) void aggregate_kernel(
    const ushort* __restrict__ sup,
    const int* __restrict__ row_ptr,
    const int* __restrict__ degv,
    const int* __restrict__ col,
    const float* __restrict__ b,
    float* __restrict__ out) {
    const int wid = threadIdx.x >> 6;
    const int lane = threadIdx.x & 63;
    const int node = blockIdx.x * 4 + wid;
    if (node >= N_NODES) return;

    const int rs = lane >> 4;   // row slot 0..3
    const int fq = lane & 15;   // feature quad

    const int beg = row_ptr[node];
    const int dg = degv[node];
    const int end = beg + PAD8(dg);

    const uint4* sp = (const uint4*)sup;

    float acc[8] = {};
    for (int base = beg; base < end; base += 64) {
        const int rem = end - base;
        const int m = rem < 64 ? rem : 64;                 // multiple of 8
        const int mycol = (lane < m) ? col[base + lane] : 0;
        const int ng16 = m >> 4;
        for (int g = 0; g < ng16; ++g) {
            uint4 v[4];
#pragma unroll
            for (int q = 0; q < 4; ++q) {
                const int s = __shfl(mycol, g * 16 + q * 4 + rs);
                v[q] = sp[(long long)s * 16 + fq];         // pads read zero row
            }
#pragma unroll
            for (int q = 0; q < 4; ++q) {
                acc[0] += blo(v[q].x); acc[1] += bhi(v[q].x);
                acc[2] += blo(v[q].y); acc[3] += bhi(v[q].y);
                acc[4] += blo(v[q].z); acc[5] += bhi(v[q].z);
                acc[6] += blo(v[q].w); acc[7] += bhi(v[q].w);
            }
        }
        if (m & 8) {                                       // 8-edge tail group
            uint4 v[2];
#pragma unroll
            for (int q = 0; q < 2; ++q) {
                const int s = __shfl(mycol, (ng16 << 4) + q * 4 + rs);
                v[q] = sp[(long long)s * 16 + fq];
            }
#pragma unroll
            for (int q = 0; q < 2; ++q) {
                acc[0] += blo(v[q].x); acc[1] += bhi(v[q].x);
                acc[2] += blo(v[q].y); acc[3] += bhi(v[q].y);
                acc[4] += blo(v[q].z); acc[5] += bhi(v[q].z);
                acc[6] += blo(v[q].w); acc[7] += bhi(v[q].w);
            }
        }
    }
    // reduce across the 4 row slots FIRST...
#pragma unroll
    for (int i = 0; i < 8; ++i) {
        acc[i] += __shfl_xor(acc[i], 16);
        acc[i] += __shfl_xor(acc[i], 32);
    }
    // ...THEN add self-loop exactly once
    {
        const uint4 v = sp[(long long)node * 16 + fq];
        acc[0] += blo(v.x); acc[1] += bhi(v.x);
        acc[2] += blo(v.y); acc[3] += bhi(v.y);
        acc[4] += blo(v.z); acc[5] += bhi(v.z);
        acc[6] += blo(v.w); acc[7] += bhi(v.w);
    }
    const float inv = 1.0f / (float)(dg + 1);
    const float4 b0 = ((const float4*)b)[fq * 2];
    const float4 b1 = ((const float4*)b)[fq * 2 + 1];
    if (rs == 0) {
        float4 r0, r1;
        r0.x = acc[0] * inv + b0.x; r0.y = acc[1] * inv + b0.y;
        r0.z = acc[2] * inv + b0.z; r0.w = acc[3] * inv + b0.w;
        r1.x = acc[4] * inv + b1.x; r1.y = acc[5] * inv + b1.y;
        r1.z = acc[6] * inv + b1.z; r1.w = acc[7] * inv + b1.w;
        float4* o4 = (float4*)out;
        o4[(long long)node * 32 + fq * 2] = r0;
        o4[(long long)node * 32 + fq * 2 + 1] = r1;
    }
}

extern "C" void kernel_launch(void* const* d_in, const int* in_sizes, int n_in,
                              void* d_out, int out_size, void* d_ws, size_t ws_size,
                              hipStream_t stream) {
    const float* x = (const float*)d_in[0];
    const int* src = (const int*)d_in[1];
    const int* dst = (const int*)d_in[2];
    const float* w = (const float*)d_in[3];
    const float* b = (const float*)d_in[4];
    float* out = (float*)d_out;

    // Workspace (~49 MB): sup 25.6 | deg .4 | row_ptr .4 | col 9.2 | Psrc 8.4 | Pdl 4.2 | wimg | ctrs
    char* p = (char*)d_ws;
    ushort* sup = (ushort*)p;    p += (((size_t)(N_NODES + 1)) * F * sizeof(ushort) + 15) & ~15ULL;
    int* deg = (int*)p;          p += ((size_t)N_NODES * sizeof(int) + 15) & ~15ULL;
    int* row_ptr = (int*)p;      p += ((size_t)N_NODES * sizeof(int) + 15) & ~15ULL;
    int* col = (int*)p;          p += ((size_t)(NE + 7 * N_NODES) * sizeof(int) + 15) & ~15ULL;
    int* Psrc = (int*)p;         p += ((size_t)NBUCK * CAP * sizeof(int) + 15) & ~15ULL;
    unsigned short* Pdl = (unsigned short*)p;  p += ((size_t)NBUCK * CAP * sizeof(unsigned short) + 15) & ~15ULL;
    ushort* wimg = (ushort*)p;   p += ((size_t)F * F * sizeof(ushort) + 15) & ~15ULL;
    int* gcnt = (int*)p;         p += ((size_t)NBUCK * sizeof(int) + 15) & ~15ULL;
    int* segalloc = (int*)p;

    prep_w<<<1, 256, 0, stream>>>(w, wimg, sup, gcnt, segalloc);
    gemm_mfma<<<(N_NODES + 127) / 128, 256, 0, stream>>>(x, wimg, sup);
    bucket_scatter2<<<NBUCK, 1024, 0, stream>>>(src, dst, gcnt, Psrc, Pdl);
    col_fill2<<<NBUCK, 1024, 0, stream>>>(Psrc, Pdl, gcnt, segalloc, deg, row_ptr, col);
    aggregate_kernel<<<(N_NODES + 3) / 4, 256, 0, stream>>>(sup, row_ptr, deg, col, b, out);
}

// Round 16
// 127.141 us; speedup vs baseline: 1.4199x; 1.0259x over previous
//
#include <hip/hip_runtime.h>

#define N_NODES 100000
#define F 128
#define NE 1600000
#define NBUCK 256
#define BSZ 391                    // nodes per bucket; 391*256 = 100096 >= N
#define CHUNK2 (NE / NBUCK)        // 6250 edges per partition chunk
#define CAP 8192                   // per-bucket region capacity (mean 6250, +24 sigma)
#define SEGCAP 16384               // LDS col-segment capacity (worst ~8K padded)
#define NGEMM ((N_NODES + 127) / 128)   // 782 gemm tiles
#define PAD8(v) (((v) + 7) & ~7)

typedef __attribute__((ext_vector_type(8))) short bf16x8;
typedef __attribute__((ext_vector_type(4))) float f32x4;

// fp32 -> bf16 round-to-nearest-even
__device__ __forceinline__ unsigned short f2bf(float f) {
    unsigned int u = __float_as_uint(f);
    return (unsigned short)((u + 0x7FFFu + ((u >> 16) & 1u)) >> 16);
}
__device__ __forceinline__ float blo(unsigned int v) { return __uint_as_float(v << 16); }
__device__ __forceinline__ float bhi(unsigned int v) { return __uint_as_float(v & 0xFFFF0000u); }

// ---------- Kernel 0: one-time prep — swizzled bf16 W^T image + zero counters/pad row ----------
__global__ __launch_bounds__(256) void prep_w(const float* __restrict__ w,
                                              ushort* __restrict__ wimg,
                                              ushort* __restrict__ sup,
                                              int* __restrict__ gcnt,
                                              int* __restrict__ segalloc) {
    const int t = threadIdx.x;
#pragma unroll
    for (int it = 0; it < 16; ++it) {
        const int f = it * 256 + t;
        const int c = f & 127;
        const int kq = f >> 7;
        ushort4 o;
        o.x = f2bf(w[(4 * kq + 0) * F + c]);
        o.y = f2bf(w[(4 * kq + 1) * F + c]);
        o.z = f2bf(w[(4 * kq + 2) * F + c]);
        o.w = f2bf(w[(4 * kq + 3) * F + c]);
        ((ushort4*)wimg)[c * 32 + (kq ^ ((c & 15) << 1))] = o;
    }
    if (t < 128) sup[(size_t)N_NODES * F + t] = 0;   // zero pad row
    if (t < NBUCK) gcnt[t] = 0;
    if (t == 0) *segalloc = 0;
}

// ---------- Fat kernel: blocks [0,NBUCK) = edge partition; [NBUCK, NBUCK+NGEMM) = GEMM ----------
__global__ __launch_bounds__(256) void gemm_scatter(
    const float* __restrict__ x, const ushort* __restrict__ wimg, ushort* __restrict__ sup,
    const int* __restrict__ src, const int* __restrict__ dst,
    int* __restrict__ gcnt, int* __restrict__ Psrc, unsigned short* __restrict__ Pdl) {
    __shared__ union U {
        struct { ushort xs[128 * 128]; ushort wt[128 * 128]; } g;   // 64 KB (gemm)
        struct { int hist[NBUCK]; int off[NBUCK]; int pos[NBUCK]; } s;  // 3 KB (scatter)
    } u;
    const int t = threadIdx.x;

    if (blockIdx.x < NBUCK) {
        // ---- scatter body (256 threads) ----
        int* hist = u.s.hist;
        int* off = u.s.off;
        int* pos = u.s.pos;
        hist[t] = 0;
        pos[t] = 0;
        __syncthreads();
        const int e0 = blockIdx.x * CHUNK2;
        for (int i = t; i < CHUNK2; i += 256)
            atomicAdd(&hist[dst[e0 + i] / BSZ], 1);
        __syncthreads();
        off[t] = atomicAdd(&gcnt[t], hist[t]);   // reserve contiguous run
        __syncthreads();
        for (int i = t; i < CHUNK2; i += 256) {
            const int d = dst[e0 + i];
            const int k = d / BSZ;
            const int r = atomicAdd(&pos[k], 1);
            const int p = k * CAP + off[k] + r;
            Psrc[p] = src[e0 + i];
            Pdl[p] = (unsigned short)(d - k * BSZ);
        }
        return;
    }

    // ---- gemm body ----
    ushort* xs = u.g.xs;
    ushort* wt = u.g.wt;
    const int rbase = (blockIdx.x - NBUCK) * 128;

    // stage pre-built W image verbatim (no conversion)
#pragma unroll
    for (int i = 0; i < 8; ++i)
        ((float4*)wt)[i * 256 + t] = ((const float4*)wimg)[i * 256 + t];
    // stage x tile as bf16, swizzled
#pragma unroll
    for (int it = 0; it < 16; ++it) {
        const int f = it * 256 + t;
        const int r = f >> 5;
        const int cg = f & 31;
        const int gr = rbase + r;
        float4 v = make_float4(0.f, 0.f, 0.f, 0.f);
        if (gr < N_NODES) v = ((const float4*)x)[(long long)gr * 32 + cg];
        ushort4 o;
        o.x = f2bf(v.x); o.y = f2bf(v.y); o.z = f2bf(v.z); o.w = f2bf(v.w);
        ((ushort4*)xs)[r * 32 + (cg ^ ((r & 15) << 1))] = o;
    }
    __syncthreads();

    const int wid = t >> 6;
    const int lane = t & 63;
    const int wr = wid >> 1;
    const int wc = wid & 1;
    const int l16 = lane & 15;
    const int kg = lane >> 4;

    f32x4 acc[4][4] = {};
    const bf16x8* xs8 = (const bf16x8*)xs;
    const bf16x8* wt8 = (const bf16x8*)wt;

#pragma unroll
    for (int ks = 0; ks < 4; ++ks) {
        const int k8 = ks * 4 + kg;
        bf16x8 a[4], bb[4];
#pragma unroll
        for (int mi = 0; mi < 4; ++mi) {
            const int r = wr * 64 + mi * 16 + l16;
            a[mi] = xs8[r * 16 + (k8 ^ (r & 15))];
        }
#pragma unroll
        for (int ni = 0; ni < 4; ++ni) {
            const int c = wc * 64 + ni * 16 + l16;
            bb[ni] = wt8[c * 16 + (k8 ^ (c & 15))];
        }
        // swapped operands: D = (x-block . W-block)^T -> row in l16, cols in regs
#pragma unroll
        for (int mi = 0; mi < 4; ++mi)
#pragma unroll
            for (int ni = 0; ni < 4; ++ni)
                acc[mi][ni] = __builtin_amdgcn_mfma_f32_16x16x32_bf16(
                    bb[ni], a[mi], acc[mi][ni], 0, 0, 0);
    }

    // epilogue: thread holds rows r = wr*64+mi*16+l16, cols wc*64+ni*16+kg*4..+3
#pragma unroll
    for (int mi = 0; mi < 4; ++mi) {
        const int r = rbase + wr * 64 + mi * 16 + l16;
        if (r < N_NODES) {
#pragma unroll
            for (int ni = 0; ni < 4; ++ni) {
                ushort4 o;
                o.x = f2bf(acc[mi][ni][0]);
                o.y = f2bf(acc[mi][ni][1]);
                o.z = f2bf(acc[mi][ni][2]);
                o.w = f2bf(acc[mi][ni][3]);
                const long long idx = ((long long)r * F + wc * 64 + ni * 16 + kg * 4) >> 2;
                ((ushort4*)sup)[idx] = o;
            }
        }
    }
}

// ---------- B: per-bucket deg count + local padded scan + bump-allocated CSR fill ----------
__global__ __launch_bounds__(1024) void col_fill2(const int* __restrict__ Psrc,
                                                  const unsigned short* __restrict__ Pdl,
                                                  const int* __restrict__ gcnt,
                                                  int* __restrict__ segalloc,
                                                  int* __restrict__ deg,
                                                  int* __restrict__ row_ptr,
                                                  int* __restrict__ col) {
    __shared__ int buf[SEGCAP];    // 64 KB
    __shared__ int c[BSZ];         // degree counts
    __shared__ int cnt[BSZ];       // rank counters
    __shared__ int sh[512];        // scan
    __shared__ int rp[BSZ];        // absolute segment start per node
    __shared__ int segbase_s;
    const int k = blockIdx.x;
    const int t = threadIdx.x;
    const int n0 = k * BSZ;
    const int nn = min(N_NODES - n0, BSZ);
    for (int i = t; i < BSZ; i += 1024) { c[i] = 0; cnt[i] = 0; }
    __syncthreads();
    const int e0 = k * CAP;
    const int ne = gcnt[k];
    for (int i = t; i < ne; i += 1024) atomicAdd(&c[Pdl[e0 + i]], 1);
    __syncthreads();
    // inclusive scan of padded degrees over 512 slots (nn <= 391)
    int myp = 0;
    if (t < 512) { myp = (t < nn) ? PAD8(c[t]) : 0; sh[t] = myp; }
    __syncthreads();
    for (int off = 1; off < 512; off <<= 1) {
        int u = 0;
        if (t < 512 && t >= off) u = sh[t - off];
        __syncthreads();
        if (t < 512) sh[t] += u;
        __syncthreads();
    }
    if (t == 511) segbase_s = atomicAdd(segalloc, sh[511]);
    __syncthreads();
    const int segbase = segbase_s;
    const int seglen = sh[511];                   // multiple of 8
    if (t < nn) {
        const int start = segbase + sh[t] - myp;  // exclusive prefix
        rp[t] = start;
        row_ptr[n0 + t] = start;
        deg[n0 + t] = c[t];
    }
    __syncthreads();
    for (int i = t; i < seglen; i += 1024) buf[i] = N_NODES;   // pad = zero row
    __syncthreads();
    for (int i = t; i < ne; i += 1024) {
        const int dl = Pdl[e0 + i];
        const int r = atomicAdd(&cnt[dl], 1);
        buf[rp[dl] - segbase + r] = Psrc[e0 + i];
    }
    __syncthreads();
    for (int i = t; i < (seglen >> 2); i += 1024)
        ((int4*)(col + segbase))[i] = ((const int4*)buf)[i];
}

// ---------- Kernel 5: gather-aggregate, branchless; end derived from PAD8(deg) ----------
__global__ __launch_bounds__(256) void aggregate_kernel(
    const ushort* __restrict__ sup,
    const int* __restrict__ row_ptr,
    const int* __restrict__ degv,
    const int* __restrict__ col,
    const float* __restrict__ b,
    float* __restrict__ out) {
    const int wid = threadIdx.x >> 6;
    const int lane = threadIdx.x & 63;
    const int node = blockIdx.x * 4 + wid;
    if (node >= N_NODES) return;

    const int rs = lane >> 4;   // row slot 0..3
    const int fq = lane & 15;   // feature quad

    const int beg = row_ptr[node];
    const int dg = degv[node];
    const int end = beg + PAD8(dg);

    const uint4* sp = (const uint4*)sup;

    float acc[8] = {};
    for (int base = beg; base < end; base += 64) {
        const int rem = end - base;
        const int m = rem < 64 ? rem : 64;                 // multiple of 8
        const int mycol = (lane < m) ? col[base + lane] : 0;
        const int ng16 = m >> 4;
        for (int g = 0; g < ng16; ++g) {
            uint4 v[4];
#pragma unroll
            for (int q = 0; q < 4; ++q) {
                const int s = __shfl(mycol, g * 16 + q * 4 + rs);
                v[q] = sp[(long long)s * 16 + fq];         // pads read zero row
            }
#pragma unroll
            for (int q = 0; q < 4; ++q) {
                acc[0] += blo(v[q].x); acc[1] += bhi(v[q].x);
                acc[2] += blo(v[q].y); acc[3] += bhi(v[q].y);
                acc[4] += blo(v[q].z); acc[5] += bhi(v[q].z);
                acc[6] += blo(v[q].w); acc[7] += bhi(v[q].w);
            }
        }
        if (m & 8) {                                       // 8-edge tail group
            uint4 v[2];
#pragma unroll
            for (int q = 0; q < 2; ++q) {
                const int s = __shfl(mycol, (ng16 << 4) + q * 4 + rs);
                v[q] = sp[(long long)s * 16 + fq];
            }
#pragma unroll
            for (int q = 0; q < 2; ++q) {
                acc[0] += blo(v[q].x); acc[1] += bhi(v[q].x);
                acc[2] += blo(v[q].y); acc[3] += bhi(v[q].y);
                acc[4] += blo(v[q].z); acc[5] += bhi(v[q].z);
                acc[6] += blo(v[q].w); acc[7] += bhi(v[q].w);
            }
        }
    }
    // reduce across the 4 row slots FIRST...
#pragma unroll
    for (int i = 0; i < 8; ++i) {
        acc[i] += __shfl_xor(acc[i], 16);
        acc[i] += __shfl_xor(acc[i], 32);
    }
    // ...THEN add self-loop exactly once
    {
        const uint4 v = sp[(long long)node * 16 + fq];
        acc[0] += blo(v.x); acc[1] += bhi(v.x);
        acc[2] += blo(v.y); acc[3] += bhi(v.y);
        acc[4] += blo(v.z); acc[5] += bhi(v.z);
        acc[6] += blo(v.w); acc[7] += bhi(v.w);
    }
    const float inv = 1.0f / (float)(dg + 1);
    const float4 b0 = ((const float4*)b)[fq * 2];
    const float4 b1 = ((const float4*)b)[fq * 2 + 1];
    if (rs == 0) {
        float4 r0, r1;
        r0.x = acc[0] * inv + b0.x; r0.y = acc[1] * inv + b0.y;
        r0.z = acc[2] * inv + b0.z; r0.w = acc[3] * inv + b0.w;
        r1.x = acc[4] * inv + b1.x; r1.y = acc[5] * inv + b1.y;
        r1.z = acc[6] * inv + b1.z; r1.w = acc[7] * inv + b1.w;
        float4* o4 = (float4*)out;
        o4[(long long)node * 32 + fq * 2] = r0;
        o4[(long long)node * 32 + fq * 2 + 1] = r1;
    }
}

extern "C" void kernel_launch(void* const* d_in, const int* in_sizes, int n_in,
                              void* d_out, int out_size, void* d_ws, size_t ws_size,
                              hipStream_t stream) {
    const float* x = (const float*)d_in[0];
    const int* src = (const int*)d_in[1];
    const int* dst = (const int*)d_in[2];
    const float* w = (const float*)d_in[3];
    const float* b = (const float*)d_in[4];
    float* out = (float*)d_out;

    // Workspace (~49 MB): sup 25.6 | deg .4 | row_ptr .4 | col 9.2 | Psrc 8.4 | Pdl 4.2 | wimg | ctrs
    char* p = (char*)d_ws;
    ushort* sup = (ushort*)p;    p += (((size_t)(N_NODES + 1)) * F * sizeof(ushort) + 15) & ~15ULL;
    int* deg = (int*)p;          p += ((size_t)N_NODES * sizeof(int) + 15) & ~15ULL;
    int* row_ptr = (int*)p;      p += ((size_t)N_NODES * sizeof(int) + 15) & ~15ULL;
    int* col = (int*)p;          p += ((size_t)(NE + 7 * N_NODES) * sizeof(int) + 15) & ~15ULL;
    int* Psrc = (int*)p;         p += ((size_t)NBUCK * CAP * sizeof(int) + 15) & ~15ULL;
    unsigned short* Pdl = (unsigned short*)p;  p += ((size_t)NBUCK * CAP * sizeof(unsigned short) + 15) & ~15ULL;
    ushort* wimg = (ushort*)p;   p += ((size_t)F * F * sizeof(ushort) + 15) & ~15ULL;
    int* gcnt = (int*)p;         p += ((size_t)NBUCK * sizeof(int) + 15) & ~15ULL;
    int* segalloc = (int*)p;

    prep_w<<<1, 256, 0, stream>>>(w, wimg, sup, gcnt, segalloc);
    gemm_scatter<<<NBUCK + NGEMM, 256, 0, stream>>>(x, wimg, sup, src, dst, gcnt, Psrc, Pdl);
    col_fill2<<<NBUCK, 1024, 0, stream>>>(Psrc, Pdl, gcnt, segalloc, deg, row_ptr, col);
    aggregate_kernel<<<(N_NODES + 3) / 4, 256, 0, stream>>>(sup, row_ptr, deg, col, b, out);
}

// Round 17
// 123.315 us; speedup vs baseline: 1.4640x; 1.0310x over previous
//
#include <hip/hip_runtime.h>

#define N_NODES 100000
#define F 128
#define NE 1600000
#define NBUCK 256
#define BSZ 391                    // nodes per bucket; 391*256 = 100096 >= N
#define CHUNK2 (NE / NBUCK)        // 6250 edges per partition chunk
#define CAP 8192                   // per-bucket region capacity (mean 6250, +24 sigma)
#define SEGCAP 16384               // LDS col-segment capacity (worst ~8K padded)
#define NGEMM ((N_NODES + 127) / 128)   // 782 gemm tiles
#define PAD8(v) (((v) + 7) & ~7)

typedef __attribute__((ext_vector_type(8))) short bf16x8;
typedef __attribute__((ext_vector_type(4))) float f32x4;

// fp32 -> bf16 round-to-nearest-even
__device__ __forceinline__ unsigned short f2bf(float f) {
    unsigned int u = __float_as_uint(f);
    return (unsigned short)((u + 0x7FFFu + ((u >> 16) & 1u)) >> 16);
}
__device__ __forceinline__ float blo(unsigned int v) { return __uint_as_float(v << 16); }
__device__ __forceinline__ float bhi(unsigned int v) { return __uint_as_float(v & 0xFFFF0000u); }

// ---------- Kernel 0: one-time prep — swizzled bf16 W^T image + zero counters/pad row ----------
__global__ __launch_bounds__(256) void prep_w(const float* __restrict__ w,
                                              ushort* __restrict__ wimg,
                                              ushort* __restrict__ sup,
                                              int* __restrict__ gcnt,
                                              int* __restrict__ segalloc) {
    const int t = threadIdx.x;
#pragma unroll
    for (int it = 0; it < 16; ++it) {
        const int f = it * 256 + t;
        const int c = f & 127;
        const int kq = f >> 7;
        ushort4 o;
        o.x = f2bf(w[(4 * kq + 0) * F + c]);
        o.y = f2bf(w[(4 * kq + 1) * F + c]);
        o.z = f2bf(w[(4 * kq + 2) * F + c]);
        o.w = f2bf(w[(4 * kq + 3) * F + c]);
        ((ushort4*)wimg)[c * 32 + (kq ^ ((c & 15) << 1))] = o;
    }
    if (t < 128) sup[(size_t)N_NODES * F + t] = 0;   // zero pad row
    if (t < NBUCK) gcnt[t] = 0;
    if (t == 0) *segalloc = 0;
}

// ---------- Fat kernel: blocks [0,NBUCK) = LDS-sorted edge partition; rest = GEMM ----------
__global__ __launch_bounds__(256) void gemm_scatter(
    const float* __restrict__ x, const ushort* __restrict__ wimg, ushort* __restrict__ sup,
    const int* __restrict__ src, const int* __restrict__ dst,
    int* __restrict__ gcnt, int* __restrict__ Psrc, unsigned short* __restrict__ Pdl) {
    __shared__ union U {
        struct { ushort xs[128 * 128]; ushort wt[128 * 128]; } g;   // 64 KB (gemm)
        struct {                                                    // ~48 KB (scatter)
            int lsrc[CHUNK2];
            unsigned short ldl[CHUNK2];
            unsigned char lk[CHUNK2];
            int hist[NBUCK]; int off[NBUCK]; int pos[NBUCK]; int lstart[NBUCK];
        } s;
    } u;
    const int t = threadIdx.x;

    if (blockIdx.x < NBUCK) {
        // ---- scatter body: LDS bucket-sort then coalesced dump ----
        u.s.hist[t] = 0;
        u.s.pos[t] = 0;
        __syncthreads();
        const int e0 = blockIdx.x * CHUNK2;
        // pass 1: histogram
        for (int i = t; i < CHUNK2; i += 256)
            atomicAdd(&u.s.hist[dst[e0 + i] / BSZ], 1);
        __syncthreads();
        const int h = u.s.hist[t];
        u.s.off[t] = atomicAdd(&gcnt[t], h);     // reserve contiguous run
        // exclusive scan of hist -> lstart
        u.s.lstart[t] = h;
        __syncthreads();
        for (int o = 1; o < NBUCK; o <<= 1) {
            const int v = (t >= o) ? u.s.lstart[t - o] : 0;
            __syncthreads();
            u.s.lstart[t] += v;
            __syncthreads();
        }
        const int myexcl = u.s.lstart[t] - h;
        __syncthreads();
        u.s.lstart[t] = myexcl;
        __syncthreads();
        // pass 2: sort into LDS
        for (int i = t; i < CHUNK2; i += 256) {
            const int d = dst[e0 + i];
            const int k = d / BSZ;
            const int r = atomicAdd(&u.s.pos[k], 1);
            const int li = u.s.lstart[k] + r;
            u.s.lsrc[li] = src[e0 + i];
            u.s.ldl[li] = (unsigned short)(d - k * BSZ);
            u.s.lk[li] = (unsigned char)k;
        }
        __syncthreads();
        // dump: consecutive i in a run -> consecutive global addrs (coalesced)
        for (int i = t; i < CHUNK2; i += 256) {
            const int k = u.s.lk[i];
            const int p = k * CAP + u.s.off[k] + (i - u.s.lstart[k]);
            Psrc[p] = u.s.lsrc[i];
            Pdl[p] = u.s.ldl[i];
        }
        return;
    }

    // ---- gemm body ----
    ushort* xs = u.g.xs;
    ushort* wt = u.g.wt;
    const int rbase = (blockIdx.x - NBUCK) * 128;

#pragma unroll
    for (int i = 0; i < 8; ++i)
        ((float4*)wt)[i * 256 + t] = ((const float4*)wimg)[i * 256 + t];
#pragma unroll
    for (int it = 0; it < 16; ++it) {
        const int f = it * 256 + t;
        const int r = f >> 5;
        const int cg = f & 31;
        const int gr = rbase + r;
        float4 v = make_float4(0.f, 0.f, 0.f, 0.f);
        if (gr < N_NODES) v = ((const float4*)x)[(long long)gr * 32 + cg];
        ushort4 o;
        o.x = f2bf(v.x); o.y = f2bf(v.y); o.z = f2bf(v.z); o.w = f2bf(v.w);
        ((ushort4*)xs)[r * 32 + (cg ^ ((r & 15) << 1))] = o;
    }
    __syncthreads();

    const int wid = t >> 6;
    const int lane = t & 63;
    const int wr = wid >> 1;
    const int wc = wid & 1;
    const int l16 = lane & 15;
    const int kg = lane >> 4;

    f32x4 acc[4][4] = {};
    const bf16x8* xs8 = (const bf16x8*)xs;
    const bf16x8* wt8 = (const bf16x8*)wt;

#pragma unroll
    for (int ks = 0; ks < 4; ++ks) {
        const int k8 = ks * 4 + kg;
        bf16x8 a[4], bb[4];
#pragma unroll
        for (int mi = 0; mi < 4; ++mi) {
            const int r = wr * 64 + mi * 16 + l16;
            a[mi] = xs8[r * 16 + (k8 ^ (r & 15))];
        }
#pragma unroll
        for (int ni = 0; ni < 4; ++ni) {
            const int c = wc * 64 + ni * 16 + l16;
            bb[ni] = wt8[c * 16 + (k8 ^ (c & 15))];
        }
        // swapped operands: D = (x-block . W-block)^T -> row in l16, cols in regs
#pragma unroll
        for (int mi = 0; mi < 4; ++mi)
#pragma unroll
            for (int ni = 0; ni < 4; ++ni)
                acc[mi][ni] = __builtin_amdgcn_mfma_f32_16x16x32_bf16(
                    bb[ni], a[mi], acc[mi][ni], 0, 0, 0);
    }

#pragma unroll
    for (int mi = 0; mi < 4; ++mi) {
        const int r = rbase + wr * 64 + mi * 16 + l16;
        if (r < N_NODES) {
#pragma unroll
            for (int ni = 0; ni < 4; ++ni) {
                ushort4 o;
                o.x = f2bf(acc[mi][ni][0]);
                o.y = f2bf(acc[mi][ni][1]);
                o.z = f2bf(acc[mi][ni][2]);
                o.w = f2bf(acc[mi][ni][3]);
                const long long idx = ((long long)r * F + wc * 64 + ni * 16 + kg * 4) >> 2;
                ((ushort4*)sup)[idx] = o;
            }
        }
    }
}

// ---------- B: per-bucket deg count + local padded scan + bump-allocated CSR fill ----------
__global__ __launch_bounds__(1024) void col_fill2(const int* __restrict__ Psrc,
                                                  const unsigned short* __restrict__ Pdl,
                                                  const int* __restrict__ gcnt,
                                                  int* __restrict__ segalloc,
                                                  int* __restrict__ deg,
                                                  int* __restrict__ row_ptr,
                                                  int* __restrict__ col) {
    __shared__ int buf[SEGCAP];    // 64 KB
    __shared__ int c[BSZ];         // degree counts
    __shared__ int cnt[BSZ];       // rank counters
    __shared__ int sh[512];        // scan
    __shared__ int rp[BSZ];        // absolute segment start per node
    __shared__ int segbase_s;
    const int k = blockIdx.x;
    const int t = threadIdx.x;
    const int n0 = k * BSZ;
    const int nn = min(N_NODES - n0, BSZ);
    for (int i = t; i < BSZ; i += 1024) { c[i] = 0; cnt[i] = 0; }
    __syncthreads();
    const int e0 = k * CAP;
    const int ne = gcnt[k];
    for (int i = t; i < ne; i += 1024) atomicAdd(&c[Pdl[e0 + i]], 1);
    __syncthreads();
    // inclusive scan of padded degrees over 512 slots (nn <= 391)
    int myp = 0;
    if (t < 512) { myp = (t < nn) ? PAD8(c[t]) : 0; sh[t] = myp; }
    __syncthreads();
    for (int off = 1; off < 512; off <<= 1) {
        int u = 0;
        if (t < 512 && t >= off) u = sh[t - off];
        __syncthreads();
        if (t < 512) sh[t] += u;
        __syncthreads();
    }
    if (t == 511) segbase_s = atomicAdd(segalloc, sh[511]);
    __syncthreads();
    const int segbase = segbase_s;
    const int seglen = sh[511];                   // multiple of 8
    if (t < nn) {
        const int start = segbase + sh[t] - myp;  // exclusive prefix
        rp[t] = start;
        row_ptr[n0 + t] = start;
        deg[n0 + t] = c[t];
    }
    __syncthreads();
    for (int i = t; i < seglen; i += 1024) buf[i] = N_NODES;   // pad = zero row
    __syncthreads();
    for (int i = t; i < ne; i += 1024) {
        const int dl = Pdl[e0 + i];
        const int r = atomicAdd(&cnt[dl], 1);
        buf[rp[dl] - segbase + r] = Psrc[e0 + i];
    }
    __syncthreads();
    for (int i = t; i < (seglen >> 2); i += 1024)
        ((int4*)(col + segbase))[i] = ((const int4*)buf)[i];
}

// ---------- Kernel 5: gather-aggregate, branchless; end derived from PAD8(deg) ----------
__global__ __launch_bounds__(256) void aggregate_kernel(
    const ushort* __restrict__ sup,
    const int* __restrict__ row_ptr,
    const int* __restrict__ degv,
    const int* __restrict__ col,
    const float* __restrict__ b,
    float* __restrict__ out) {
    const int wid = threadIdx.x >> 6;
    const int lane = threadIdx.x & 63;
    const int node = blockIdx.x * 4 + wid;
    if (node >= N_NODES) return;

    const int rs = lane >> 4;   // row slot 0..3
    const int fq = lane & 15;   // feature quad

    const int beg = row_ptr[node];
    const int dg = degv[node];
    const int end = beg + PAD8(dg);

    const uint4* sp = (const uint4*)sup;

    float acc[8] = {};
    for (int base = beg; base < end; base += 64) {
        const int rem = end - base;
        const int m = rem < 64 ? rem : 64;                 // multiple of 8
        const int mycol = (lane < m) ? col[base + lane] : 0;
        const int ng16 = m >> 4;
        for (int g = 0; g < ng16; ++g) {
            uint4 v[4];
#pragma unroll
            for (int q = 0; q < 4; ++q) {
                const int s = __shfl(mycol, g * 16 + q * 4 + rs);
                v[q] = sp[(long long)s * 16 + fq];         // pads read zero row
            }
#pragma unroll
            for (int q = 0; q < 4; ++q) {
                acc[0] += blo(v[q].x); acc[1] += bhi(v[q].x);
                acc[2] += blo(v[q].y); acc[3] += bhi(v[q].y);
                acc[4] += blo(v[q].z); acc[5] += bhi(v[q].z);
                acc[6] += blo(v[q].w); acc[7] += bhi(v[q].w);
            }
        }
        if (m & 8) {                                       // 8-edge tail group
            uint4 v[2];
#pragma unroll
            for (int q = 0; q < 2; ++q) {
                const int s = __shfl(mycol, (ng16 << 4) + q * 4 + rs);
                v[q] = sp[(long long)s * 16 + fq];
            }
#pragma unroll
            for (int q = 0; q < 2; ++q) {
                acc[0] += blo(v[q].x); acc[1] += bhi(v[q].x);
                acc[2] += blo(v[q].y); acc[3] += bhi(v[q].y);
                acc[4] += blo(v[q].z); acc[5] += bhi(v[q].z);
                acc[6] += blo(v[q].w); acc[7] += bhi(v[q].w);
            }
        }
    }
    // reduce across the 4 row slots FIRST...
#pragma unroll
    for (int i = 0; i < 8; ++i) {
        acc[i] += __shfl_xor(acc[i], 16);
        acc[i] += __shfl_xor(acc[i], 32);
    }
    // ...THEN add self-loop exactly once
    {
        const uint4 v = sp[(long long)node * 16 + fq];
        acc[0] += blo(v.x); acc[1] += bhi(v.x);
        acc[2] += blo(v.y); acc[3] += bhi(v.y);
        acc[4] += blo(v.z); acc[5] += bhi(v.z);
        acc[6] += blo(v.w); acc[7] += bhi(v.w);
    }
    const float inv = 1.0f / (float)(dg + 1);
    const float4 b0 = ((const float4*)b)[fq * 2];
    const float4 b1 = ((const float4*)b)[fq * 2 + 1];
    if (rs == 0) {
        float4 r0, r1;
        r0.x = acc[0] * inv + b0.x; r0.y = acc[1] * inv + b0.y;
        r0.z = acc[2] * inv + b0.z; r0.w = acc[3] * inv + b0.w;
        r1.x = acc[4] * inv + b1.x; r1.y = acc[5] * inv + b1.y;
        r1.z = acc[6] * inv + b1.z; r1.w = acc[7] * inv + b1.w;
        float4* o4 = (float4*)out;
        o4[(long long)node * 32 + fq * 2] = r0;
        o4[(long long)node * 32 + fq * 2 + 1] = r1;
    }
}

extern "C" void kernel_launch(void* const* d_in, const int* in_sizes, int n_in,
                              void* d_out, int out_size, void* d_ws, size_t ws_size,
                              hipStream_t stream) {
    const float* x = (const float*)d_in[0];
    const int* src = (const int*)d_in[1];
    const int* dst = (const int*)d_in[2];
    const float* w = (const float*)d_in[3];
    const float* b = (const float*)d_in[4];
    float* out = (float*)d_out;

    // Workspace (~49 MB): sup 25.6 | deg .4 | row_ptr .4 | col 9.2 | Psrc 8.4 | Pdl 4.2 | wimg | ctrs
    char* p = (char*)d_ws;
    ushort* sup = (ushort*)p;    p += (((size_t)(N_NODES + 1)) * F * sizeof(ushort) + 15) & ~15ULL;
    int* deg = (int*)p;          p += ((size_t)N_NODES * sizeof(int) + 15) & ~15ULL;
    int* row_ptr = (int*)p;      p += ((size_t)N_NODES * sizeof(int) + 15) & ~15ULL;
    int* col = (int*)p;          p += ((size_t)(NE + 7 * N_NODES) * sizeof(int) + 15) & ~15ULL;
    int* Psrc = (int*)p;         p += ((size_t)NBUCK * CAP * sizeof(int) + 15) & ~15ULL;
    unsigned short* Pdl = (unsigned short*)p;  p += ((size_t)NBUCK * CAP * sizeof(unsigned short) + 15) & ~15ULL;
    ushort* wimg = (ushort*)p;   p += ((size_t)F * F * sizeof(ushort) + 15) & ~15ULL;
    int* gcnt = (int*)p;         p += ((size_t)NBUCK * sizeof(int) + 15) & ~15ULL;
    int* segalloc = (int*)p;

    prep_w<<<1, 256, 0, stream>>>(w, wimg, sup, gcnt, segalloc);
    gemm_scatter<<<NBUCK + NGEMM, 256, 0, stream>>>(x, wimg, sup, src, dst, gcnt, Psrc, Pdl);
    col_fill2<<<NBUCK, 1024, 0, stream>>>(Psrc, Pdl, gcnt, segalloc, deg, row_ptr, col);
    aggregate_kernel<<<(N_NODES + 3) / 4, 256, 0, stream>>>(sup, row_ptr, deg, col, b, out);
}